// Round 1
// baseline (2773.741 us; speedup 1.0000x reference)
//
#include <hip/hip_runtime.h>
#include <hip/hip_bf16.h>
#include <math.h>

// ---------------------------------------------------------------------------
// TransformerBlock (Restormer-style) on MI355X — round 1: correct fp32 baseline
//
// B=4, C=192, H=W=128 (HW=16384), HEADS=8, head_dim=24, HIDDEN=510.
// Strategy: per-batch pipeline (batches independent), workspace reused across
// batches (~126 MB required). fp32 everywhere (threshold permits bf16 later).
//
// ws layout (float offsets), per-batch buffers reused for all 4 batches:
//   y      @ 0          (3,145,728)   LN output / attention output (reused)
//   xa     @ 3,145,728  (3,145,728)   first-residual output
//   qkv_a  @ 6,291,456  (9,437,184)   conv1x1 qkv out
//   qkv_b  @ 15,728,640 (9,437,184)   dwconv qkv out (q|k|v channel blocks)
//   h      @ 6,291,456  (16,711,680)  FFN conv1x1 out (overlaps dead qkv_a/b)
//   g      @ 23,003,136 (8,355,840)   gated FFN activation
//   nrm    @ 31,358,976 (1,536)       [4 batches][384] L2 norms of q,k rows
//   G      @ 31,360,512 (18,432)      [4][8][24][24] Gram (atomic split-K)
//   P      @ 31,378,944 (18,432)      [4][8][24][24] softmax probs
// total ≈ 31.40M floats ≈ 125.6 MB
// ---------------------------------------------------------------------------

#define HW_ 16384
#define C_ 192

// ---- channel LayerNorm: per-pixel mean/var over 192 channels ---------------
__global__ __launch_bounds__(512) void ln_kernel(
    const float* __restrict__ x, const float* __restrict__ w,
    const float* __restrict__ bi, float* __restrict__ y) {
  const int tx = threadIdx.x & 63;        // pixel within block
  const int ty = threadIdx.x >> 6;        // channel group 0..7
  const int p = blockIdx.x * 64 + tx;
  __shared__ float s_sum[8][64], s_sq[8][64];
  float s = 0.f, s2 = 0.f;
  for (int c = ty; c < C_; c += 8) {
    float v = x[c * HW_ + p];
    s += v; s2 += v * v;
  }
  s_sum[ty][tx] = s; s_sq[ty][tx] = s2;
  __syncthreads();
  float ts = 0.f, ts2 = 0.f;
  #pragma unroll
  for (int u = 0; u < 8; u++) { ts += s_sum[u][tx]; ts2 += s_sq[u][tx]; }
  const float mu = ts * (1.f / 192.f);
  const float var = ts2 * (1.f / 192.f) - mu * mu;
  const float inv = rsqrtf(var + 1e-5f);
  for (int c = ty; c < C_; c += 8) {
    float v = x[c * HW_ + p];
    y[c * HW_ + p] = (v - mu) * inv * w[c] + bi[c];
  }
}

// ---- tiled fp32 GEMM: D[M,N] = A[M,K] @ B[K,N] (+ Cres) --------------------
// 128x128 tile, BK=8, 256 threads, 8x8 microtile. N must be multiple of 128.
__global__ __launch_bounds__(256) void gemm_kernel(
    const float* __restrict__ A, const float* __restrict__ B,
    const float* __restrict__ Cres, float* __restrict__ D,
    int M, int N, int K) {
  __shared__ float As[128][8];   // [m][kk] — conflict-free write & broadcast read
  __shared__ float Bs[8][128];
  const int tid = threadIdx.x;
  const int tx = tid & 15, ty = tid >> 4;
  const int row0 = blockIdx.y * 128, col0 = blockIdx.x * 128;
  float acc[8][8];
  #pragma unroll
  for (int i = 0; i < 8; i++)
    #pragma unroll
    for (int j = 0; j < 8; j++) acc[i][j] = 0.f;

  for (int k0 = 0; k0 < K; k0 += 8) {
    #pragma unroll
    for (int l = 0; l < 4; l++) {
      int t = tid + l * 256;
      int kk = t & 7, m = t >> 3;
      int gm = row0 + m, gk = k0 + kk;
      As[m][kk] = (gm < M && gk < K) ? A[gm * K + gk] : 0.f;
    }
    #pragma unroll
    for (int l = 0; l < 4; l++) {
      int t = tid + l * 256;
      int n = t & 127, kk = t >> 7;
      int gk = k0 + kk;
      Bs[kk][n] = (gk < K) ? B[gk * N + col0 + n] : 0.f;
    }
    __syncthreads();
    #pragma unroll
    for (int kk = 0; kk < 8; kk++) {
      float a[8], bb[8];
      #pragma unroll
      for (int i = 0; i < 8; i++) a[i] = As[ty + 16 * i][kk];
      #pragma unroll
      for (int j = 0; j < 8; j++) bb[j] = Bs[kk][tx + 16 * j];
      #pragma unroll
      for (int i = 0; i < 8; i++)
        #pragma unroll
        for (int j = 0; j < 8; j++) acc[i][j] += a[i] * bb[j];
    }
    __syncthreads();
  }
  #pragma unroll
  for (int i = 0; i < 8; i++) {
    int gm = row0 + ty + 16 * i;
    if (gm >= M) continue;
    #pragma unroll
    for (int j = 0; j < 8; j++) {
      int idx = gm * N + col0 + tx + 16 * j;
      float v = acc[i][j];
      if (Cres) v += Cres[idx];
      D[idx] = v;
    }
  }
}

// ---- depthwise 3x3, SAME padding ------------------------------------------
__global__ __launch_bounds__(256) void dw_kernel(
    const float* __restrict__ in, const float* __restrict__ wdw,
    float* __restrict__ out, int H, int W) {
  const int c = blockIdx.z;
  const int xq = blockIdx.x * 64 + (threadIdx.x & 63);
  const int yq = blockIdx.y * 4 + (threadIdx.x >> 6);
  const float* ip = in + c * H * W;
  const float* wp = wdw + c * 9;
  float acc = 0.f;
  #pragma unroll
  for (int ky = 0; ky < 3; ky++) {
    int yy = yq + ky - 1;
    if (yy < 0 || yy >= H) continue;
    #pragma unroll
    for (int kx = 0; kx < 3; kx++) {
      int xx = xq + kx - 1;
      if (xx < 0 || xx >= W) continue;
      acc += ip[yy * W + xx] * wp[ky * 3 + kx];
    }
  }
  out[c * H * W + yq * W + xq] = acc;
}

// ---- L2 norms of q,k rows (384 rows of 16384) ------------------------------
__global__ __launch_bounds__(256) void rownorm_kernel(
    const float* __restrict__ qk, float* __restrict__ nrm) {
  const int r = blockIdx.x;   // 0..383 (channels 0..383 of qkv_b = q|k)
  const float* p = qk + r * HW_;
  float s = 0.f;
  for (int i = threadIdx.x; i < HW_; i += 256) { float v = p[i]; s += v * v; }
  #pragma unroll
  for (int off = 32; off > 0; off >>= 1) s += __shfl_down(s, off, 64);
  __shared__ float wsum[4];
  const int lane = threadIdx.x & 63, wv = threadIdx.x >> 6;
  if (lane == 0) wsum[wv] = s;
  __syncthreads();
  if (threadIdx.x == 0)
    nrm[r] = sqrtf(wsum[0] + wsum[1] + wsum[2] + wsum[3]);
}

// ---- Gram: G[h][d][c] += sum_e q[h,d,e]*k[h,c,e] (split-K over e, atomics) -
__global__ __launch_bounds__(256) void gram_kernel(
    const float* __restrict__ qkv, float* __restrict__ G) {
  const int h = blockIdx.x, chunk = blockIdx.y;  // chunk covers 512 e
  const float* qb = qkv + (h * 24) * HW_;
  const float* kb = qkv + (192 + h * 24) * HW_;
  __shared__ float qs[24][129], ks[24][129];
  const int tid = threadIdx.x;
  const int p0 = tid, p1 = tid + 256, p2 = tid + 512;
  const int d0 = p0 / 24, c0 = p0 % 24;
  const int d1 = p1 / 24, c1 = p1 % 24;
  const int d2 = (p2 < 576) ? p2 / 24 : 0, c2 = (p2 < 576) ? p2 % 24 : 0;
  float a0 = 0.f, a1 = 0.f, a2 = 0.f;
  const int e_base = chunk * 512;
  for (int e0 = e_base; e0 < e_base + 512; e0 += 128) {
    for (int t = tid; t < 24 * 128; t += 256) {
      int r = t >> 7, col = t & 127;
      qs[r][col] = qb[r * HW_ + e0 + col];
      ks[r][col] = kb[r * HW_ + e0 + col];
    }
    __syncthreads();
    for (int e = 0; e < 128; e++) {
      a0 += qs[d0][e] * ks[c0][e];
      a1 += qs[d1][e] * ks[c1][e];
      if (p2 < 576) a2 += qs[d2][e] * ks[c2][e];
    }
    __syncthreads();
  }
  atomicAdd(&G[h * 576 + p0], a0);
  atomicAdd(&G[h * 576 + p1], a1);
  if (p2 < 576) atomicAdd(&G[h * 576 + p2], a2);
}

// ---- softmax over c of G*temp/(|q||k|) ------------------------------------
__global__ __launch_bounds__(256) void softmax_kernel(
    const float* __restrict__ G, const float* __restrict__ nrm,
    const float* __restrict__ temp, float* __restrict__ P) {
  const int t = threadIdx.x;
  if (t >= 192) return;
  const int h = t / 24, d = t % 24;
  const float nq = fmaxf(nrm[h * 24 + d], 1e-12f);
  const float tp = temp[h];
  float row[24];
  float mx = -1e30f;
  #pragma unroll
  for (int c = 0; c < 24; c++) {
    float nk = fmaxf(nrm[192 + h * 24 + c], 1e-12f);
    float v = G[h * 576 + d * 24 + c] * tp / (nq * nk);
    row[c] = v; mx = fmaxf(mx, v);
  }
  float s = 0.f;
  #pragma unroll
  for (int c = 0; c < 24; c++) { float e = expf(row[c] - mx); row[c] = e; s += e; }
  const float inv = 1.f / s;
  #pragma unroll
  for (int c = 0; c < 24; c++) P[h * 576 + d * 24 + c] = row[c] * inv;
}

// ---- out[h,d,e] = sum_c P[h,d,c] * v[h,c,e] -------------------------------
__global__ __launch_bounds__(256) void pv_kernel(
    const float* __restrict__ P, const float* __restrict__ qkv,
    float* __restrict__ out) {
  const int h = blockIdx.x;
  const int e = blockIdx.y * 256 + threadIdx.x;
  __shared__ float Ps[576];
  for (int t = threadIdx.x; t < 576; t += 256) Ps[t] = P[h * 576 + t];
  __syncthreads();
  const float* vb = qkv + (384 + h * 24) * HW_;
  float acc[24];
  #pragma unroll
  for (int d = 0; d < 24; d++) acc[d] = 0.f;
  for (int c = 0; c < 24; c++) {
    float v = vb[c * HW_ + e];
    #pragma unroll
    for (int d = 0; d < 24; d++) acc[d] += Ps[d * 24 + c] * v;
  }
  float* ob = out + (h * 24) * HW_;
  #pragma unroll
  for (int d = 0; d < 24; d++) ob[d * HW_ + e] = acc[d];
}

// ---- fused depthwise 3x3 + exact-GELU gate --------------------------------
__global__ __launch_bounds__(256) void dwgate_kernel(
    const float* __restrict__ h, const float* __restrict__ wdw,
    float* __restrict__ g, int H, int W) {
  const int c = blockIdx.z;   // 0..509
  const int xq = blockIdx.x * 64 + (threadIdx.x & 63);
  const int yq = blockIdx.y * 4 + (threadIdx.x >> 6);
  const float* ha = h + c * H * W;
  const float* hb = h + (c + 510) * H * W;
  const float* wa = wdw + c * 9;
  const float* wb = wdw + (c + 510) * 9;
  float s1 = 0.f, s2 = 0.f;
  #pragma unroll
  for (int ky = 0; ky < 3; ky++) {
    int yy = yq + ky - 1;
    if (yy < 0 || yy >= H) continue;
    #pragma unroll
    for (int kx = 0; kx < 3; kx++) {
      int xx = xq + kx - 1;
      if (xx < 0 || xx >= W) continue;
      int o = yy * W + xx;
      s1 += ha[o] * wa[ky * 3 + kx];
      s2 += hb[o] * wb[ky * 3 + kx];
    }
  }
  const float ge = 0.5f * s1 * (1.f + erff(s1 * 0.70710678118654752f));
  g[c * H * W + yq * W + xq] = ge * s2;
}

// ---------------------------------------------------------------------------
extern "C" void kernel_launch(void* const* d_in, const int* in_sizes, int n_in,
                              void* d_out, int out_size, void* d_ws, size_t ws_size,
                              hipStream_t stream) {
  const float* x     = (const float*)d_in[0];
  const float* temp  = (const float*)d_in[1];
  const float* ln1w  = (const float*)d_in[2];
  const float* ln1b  = (const float*)d_in[3];
  const float* ln2w  = (const float*)d_in[4];
  const float* ln2b  = (const float*)d_in[5];
  const float* wqkv  = (const float*)d_in[6];
  const float* wqkvdw= (const float*)d_in[7];
  const float* wproj = (const float*)d_in[8];
  const float* win   = (const float*)d_in[9];
  const float* wdw   = (const float*)d_in[10];
  const float* wout  = (const float*)d_in[11];
  float* out = (float*)d_out;
  float* ws  = (float*)d_ws;

  const int HW = 16384;
  const int HWC = 192 * HW;

  float* y    = ws + 0;
  float* xa   = ws + 3145728;
  float* qkva = ws + 6291456;
  float* qkvb = ws + 15728640;
  float* hbuf = ws + 6291456;    // overlaps dead qkv_a/qkv_b
  float* gbuf = ws + 23003136;
  float* nrm  = ws + 31358976;   // [4][384]
  float* G    = ws + 31360512;   // [4][8][24][24]
  float* P    = ws + 31378944;   // [4][8][24][24]

  // zero Gram accumulators (atomic split-K targets) for all batches
  hipMemsetAsync(G, 0, 4 * 8 * 576 * sizeof(float), stream);

  for (int b = 0; b < 4; b++) {
    const float* xb = x + b * HWC;
    float* outb = out + b * HWC;
    float* nrmb = nrm + b * 384;
    float* Gb = G + b * 4608;
    float* Pb = P + b * 4608;

    // 1. y = LN1(x_b)
    ln_kernel<<<256, 512, 0, stream>>>(xb, ln1w, ln1b, y);
    // 2. qkv_a = w_qkv @ y   (576 x 16384)
    gemm_kernel<<<dim3(128, 5), 256, 0, stream>>>(wqkv, y, nullptr, qkva,
                                                  576, HW, 192);
    // 3. qkv_b = dwconv3x3(qkv_a)
    dw_kernel<<<dim3(2, 32, 576), 256, 0, stream>>>(qkva, wqkvdw, qkvb, 128, 128);
    // 4. L2 norms of q,k rows
    rownorm_kernel<<<384, 256, 0, stream>>>(qkvb, nrmb);
    // 5. Gram matrices per head (split-K atomics)
    gram_kernel<<<dim3(8, 32), 256, 0, stream>>>(qkvb, Gb);
    // 6. P = softmax(G * temp / (|q||k|))
    softmax_kernel<<<1, 256, 0, stream>>>(Gb, nrmb, temp, Pb);
    // 7. y = P @ v   (attention output, NCHW channel = h*24+d)
    pv_kernel<<<dim3(8, 64), 256, 0, stream>>>(Pb, qkvb, y);
    // 8. xa = x_b + w_proj @ y
    gemm_kernel<<<dim3(128, 2), 256, 0, stream>>>(wproj, y, xb, xa,
                                                  192, HW, 192);
    // 9. y = LN2(xa)
    ln_kernel<<<256, 512, 0, stream>>>(xa, ln2w, ln2b, y);
    // 10. h = w_in @ y   (1020 x 16384)
    gemm_kernel<<<dim3(128, 8), 256, 0, stream>>>(win, y, nullptr, hbuf,
                                                  1020, HW, 192);
    // 11. g = gelu(dw(h)[0:510]) * dw(h)[510:1020]
    dwgate_kernel<<<dim3(2, 32, 510), 256, 0, stream>>>(hbuf, wdw, gbuf, 128, 128);
    // 12. out_b = xa + w_out @ g
    gemm_kernel<<<dim3(128, 2), 256, 0, stream>>>(wout, gbuf, xa, outb,
                                                  192, HW, 510);
  }
}

// Round 2
// 2131.528 us; speedup vs baseline: 1.3013x; 1.3013x over previous
//
#include <hip/hip_runtime.h>
#include <hip/hip_bf16.h>
#include <math.h>

// ---------------------------------------------------------------------------
// Round 2: bf16 MFMA GEMMs + bf16 glue, transposed-activation layout.
//
// B=4, C=192, HW=16384, HEADS=8, d=24, HIDDEN=510. Per-batch loop (buffers
// reused; ws ≈ 74.3 MB, under the 126 MB known to work).
//
// Layouts:
//   weights     bf16 [M][K] (w_in padded to 1024 rows, w_out to K=512)
//   activations feeding GEMM-B: bf16 [pixel][channel] ("_t" transposed)
//   qkva/qkvb/h: bf16 [channel][pixel] (standard, for depthwise/attention)
//   xa, out: fp32 [channel][pixel]
// ---------------------------------------------------------------------------

#define HW_ 16384

typedef __attribute__((ext_vector_type(8))) short bf16x8;
typedef __attribute__((ext_vector_type(4))) float f32x4;
typedef __attribute__((ext_vector_type(4))) int i32x4;

union Pack8 { __hip_bfloat16 h[8]; i32x4 v; };

// ---- weight fp32 -> bf16 conversion (with padding) -------------------------
__global__ __launch_bounds__(256) void convert_weights(
    const float* __restrict__ wqkv, const float* __restrict__ wproj,
    const float* __restrict__ win, const float* __restrict__ wout,
    __hip_bfloat16* __restrict__ oq, __hip_bfloat16* __restrict__ op,
    __hip_bfloat16* __restrict__ oi, __hip_bfloat16* __restrict__ oo) {
  const int i = blockIdx.x * 256 + threadIdx.x;
  if (i < 110592) oq[i] = __float2bfloat16(wqkv[i]);            // 576x192
  if (i < 36864)  op[i] = __float2bfloat16(wproj[i]);           // 192x192
  if (i < 196608) {                                             // 1024x192 pad
    int m = i / 192, k = i - m * 192;
    oi[i] = __float2bfloat16(m < 1020 ? win[m * 192 + k] : 0.f);
  }
  if (i < 98304) {                                              // 192x512 pad
    int m = i >> 9, k = i & 511;
    oo[i] = __float2bfloat16(k < 510 ? wout[m * 510 + k] : 0.f);
  }
}

// ---- channel LN -> transposed bf16 output [p][192] -------------------------
__global__ __launch_bounds__(256) void ln_t_kernel(
    const float* __restrict__ x, const float* __restrict__ w,
    const float* __restrict__ bi, __hip_bfloat16* __restrict__ yt) {
  __shared__ float tile[192][65];
  __shared__ float psum[4][64], psq[4][64];
  __shared__ float mu_s[64], inv_s[64];
  const int tid = threadIdx.x;
  const int p0 = blockIdx.x * 64;
  for (int idx = tid; idx < 192 * 64; idx += 256) {
    int c = idx >> 6, p = idx & 63;
    tile[c][p] = x[c * HW_ + p0 + p];
  }
  __syncthreads();
  const int tx = tid & 63, ty = tid >> 6;
  float s = 0.f, s2 = 0.f;
  for (int c = ty * 48; c < ty * 48 + 48; c++) {
    float v = tile[c][tx]; s += v; s2 += v * v;
  }
  psum[ty][tx] = s; psq[ty][tx] = s2;
  __syncthreads();
  if (ty == 0) {
    float ts = psum[0][tx] + psum[1][tx] + psum[2][tx] + psum[3][tx];
    float ts2 = psq[0][tx] + psq[1][tx] + psq[2][tx] + psq[3][tx];
    float mu = ts * (1.f / 192.f);
    float var = ts2 * (1.f / 192.f) - mu * mu;
    mu_s[tx] = mu; inv_s[tx] = rsqrtf(var + 1e-5f);
  }
  __syncthreads();
  for (int idx = tid; idx < 64 * 24; idx += 256) {
    int c8 = idx % 24, p = idx / 24;
    float mu = mu_s[p], inv = inv_s[p];
    Pack8 pk;
    #pragma unroll
    for (int u = 0; u < 8; u++) {
      int c = c8 * 8 + u;
      pk.h[u] = __float2bfloat16((tile[c][p] - mu) * inv * w[c] + bi[c]);
    }
    *(i32x4*)&yt[(size_t)(p0 + p) * 192 + c8 * 8] = pk.v;
  }
}

// ---- MFMA GEMM: D[M][N] = A[M][K] @ B_t[N][K]^T (+res) ---------------------
// EPI 0: D bf16 [M][N].  EPI 1: D fp32 [M][N], += Cres fp32.
// BM=64, BN=128, BK=64; 256 threads = 4 waves (2 m-waves x 2 n-waves).
template <int EPI>
__global__ __launch_bounds__(256) void mfma_gemm(
    const __hip_bfloat16* __restrict__ A, const __hip_bfloat16* __restrict__ B,
    const float* __restrict__ Cres, void* __restrict__ Dout,
    int M, int N, int K) {
  __shared__ __align__(16) __hip_bfloat16 As[64][72];
  __shared__ __align__(16) __hip_bfloat16 Bs[128][72];
  const int tid = threadIdx.x;
  const int wave = tid >> 6, lane = tid & 63;
  const int quad = lane >> 4, lr = lane & 15;
  const int wm = (wave & 1) * 32, wn = (wave >> 1) * 64;
  const int row0 = blockIdx.x * 64, col0 = blockIdx.y * 128;

  f32x4 acc[2][4];
  #pragma unroll
  for (int i = 0; i < 2; i++)
    #pragma unroll
    for (int j = 0; j < 4; j++) acc[i][j] = (f32x4){0.f, 0.f, 0.f, 0.f};

  for (int k0 = 0; k0 < K; k0 += 64) {
    #pragma unroll
    for (int l = 0; l < 2; l++) {
      int t = tid + l * 256;
      int row = t >> 3, ch = t & 7;
      i32x4 v = *(const i32x4*)(A + (size_t)(row0 + row) * K + k0 + ch * 8);
      *(i32x4*)&As[row][ch * 8] = v;
    }
    #pragma unroll
    for (int l = 0; l < 4; l++) {
      int t = tid + l * 256;
      int row = t >> 3, ch = t & 7;
      i32x4 v = *(const i32x4*)(B + (size_t)(col0 + row) * K + k0 + ch * 8);
      *(i32x4*)&Bs[row][ch * 8] = v;
    }
    __syncthreads();
    #pragma unroll
    for (int ks = 0; ks < 2; ks++) {
      bf16x8 a0 = *(const bf16x8*)&As[wm + lr][ks * 32 + quad * 8];
      bf16x8 a1 = *(const bf16x8*)&As[wm + 16 + lr][ks * 32 + quad * 8];
      #pragma unroll
      for (int j = 0; j < 4; j++) {
        bf16x8 bb = *(const bf16x8*)&Bs[wn + j * 16 + lr][ks * 32 + quad * 8];
        acc[0][j] = __builtin_amdgcn_mfma_f32_16x16x32_bf16(a0, bb, acc[0][j], 0, 0, 0);
        acc[1][j] = __builtin_amdgcn_mfma_f32_16x16x32_bf16(a1, bb, acc[1][j], 0, 0, 0);
      }
    }
    __syncthreads();
  }

  #pragma unroll
  for (int i = 0; i < 2; i++) {
    #pragma unroll
    for (int r = 0; r < 4; r++) {
      int gm = row0 + wm + i * 16 + quad * 4 + r;
      if (gm >= M) continue;
      #pragma unroll
      for (int j = 0; j < 4; j++) {
        int gn = col0 + wn + j * 16 + lr;
        size_t idx = (size_t)gm * N + gn;
        if (EPI == 0) {
          ((__hip_bfloat16*)Dout)[idx] = __float2bfloat16(acc[i][j][r]);
        } else {
          ((float*)Dout)[idx] = acc[i][j][r] + Cres[idx];
        }
      }
    }
  }
}

// ---- depthwise 3x3 (bf16) + fused sum-of-squares for q,k channels ----------
__global__ __launch_bounds__(256) void dw_kernel(
    const __hip_bfloat16* __restrict__ in, const float* __restrict__ wdw,
    __hip_bfloat16* __restrict__ out, float* __restrict__ nrm2) {
  const int c = blockIdx.z;
  const int xq = blockIdx.x * 64 + (threadIdx.x & 63);
  const int yq = blockIdx.y * 4 + (threadIdx.x >> 6);
  const __hip_bfloat16* ip = in + (size_t)c * HW_;
  const float* wp = wdw + c * 9;
  float acc = 0.f;
  #pragma unroll
  for (int ky = 0; ky < 3; ky++) {
    int yy = yq + ky - 1;
    if (yy < 0 || yy >= 128) continue;
    #pragma unroll
    for (int kx = 0; kx < 3; kx++) {
      int xx = xq + kx - 1;
      if (xx < 0 || xx >= 128) continue;
      acc += (float)ip[yy * 128 + xx] * wp[ky * 3 + kx];
    }
  }
  out[(size_t)c * HW_ + yq * 128 + xq] = __float2bfloat16(acc);
  if (c < 384) {
    float s = acc * acc;
    #pragma unroll
    for (int off = 32; off > 0; off >>= 1) s += __shfl_down(s, off, 64);
    if ((threadIdx.x & 63) == 0) atomicAdd(&nrm2[c], s);
  }
}

// ---- Gram: G[h][d][c] += sum_e q[h,d,e]*k[h,c,e] ---------------------------
__global__ __launch_bounds__(256) void gram_kernel(
    const __hip_bfloat16* __restrict__ qkv, float* __restrict__ G) {
  const int h = blockIdx.x, chunk = blockIdx.y;
  const __hip_bfloat16* qb = qkv + (size_t)(h * 24) * HW_;
  const __hip_bfloat16* kb = qkv + (size_t)(192 + h * 24) * HW_;
  __shared__ float qs[24][129], ks[24][129];
  const int tid = threadIdx.x;
  const int p0 = tid, p1 = tid + 256, p2 = tid + 512;
  const int d0 = p0 / 24, c0 = p0 % 24;
  const int d1 = p1 / 24, c1 = p1 % 24;
  const int d2 = (p2 < 576) ? p2 / 24 : 0, c2 = (p2 < 576) ? p2 % 24 : 0;
  float a0 = 0.f, a1 = 0.f, a2 = 0.f;
  const int e_base = chunk * 512;
  for (int e0 = e_base; e0 < e_base + 512; e0 += 128) {
    for (int t = tid; t < 24 * 128; t += 256) {
      int r = t >> 7, col = t & 127;
      qs[r][col] = (float)qb[(size_t)r * HW_ + e0 + col];
      ks[r][col] = (float)kb[(size_t)r * HW_ + e0 + col];
    }
    __syncthreads();
    for (int e = 0; e < 128; e++) {
      a0 += qs[d0][e] * ks[c0][e];
      a1 += qs[d1][e] * ks[c1][e];
      if (p2 < 576) a2 += qs[d2][e] * ks[c2][e];
    }
    __syncthreads();
  }
  atomicAdd(&G[h * 576 + p0], a0);
  atomicAdd(&G[h * 576 + p1], a1);
  if (p2 < 576) atomicAdd(&G[h * 576 + p2], a2);
}

// ---- softmax over c of G*temp/(|q||k|), norms from nrm2 --------------------
__global__ __launch_bounds__(256) void softmax_kernel(
    const float* __restrict__ G, const float* __restrict__ nrm2,
    const float* __restrict__ temp, float* __restrict__ P) {
  const int t = threadIdx.x;
  if (t >= 192) return;
  const int h = t / 24, d = t % 24;
  const float nq = fmaxf(sqrtf(nrm2[h * 24 + d]), 1e-12f);
  const float tp = temp[h];
  float row[24];
  float mx = -1e30f;
  #pragma unroll
  for (int c = 0; c < 24; c++) {
    float nk = fmaxf(sqrtf(nrm2[192 + h * 24 + c]), 1e-12f);
    float v = G[h * 576 + d * 24 + c] * tp / (nq * nk);
    row[c] = v; mx = fmaxf(mx, v);
  }
  float s = 0.f;
  #pragma unroll
  for (int c = 0; c < 24; c++) { float e = expf(row[c] - mx); row[c] = e; s += e; }
  const float inv = 1.f / s;
  #pragma unroll
  for (int c = 0; c < 24; c++) P[h * 576 + d * 24 + c] = row[c] * inv;
}

// ---- out_t[e][h*24+d] = sum_c P[h,d,c]*v[h,c,e]  (bf16 transposed out) -----
__global__ __launch_bounds__(256) void pv_kernel(
    const float* __restrict__ P, const __hip_bfloat16* __restrict__ qkv,
    __hip_bfloat16* __restrict__ yt) {
  const int hh = blockIdx.x;
  const int e = blockIdx.y * 256 + threadIdx.x;
  __shared__ float Ps[576];
  for (int t = threadIdx.x; t < 576; t += 256) Ps[t] = P[hh * 576 + t];
  __syncthreads();
  const __hip_bfloat16* vb = qkv + (size_t)(384 + hh * 24) * HW_;
  float acc[24];
  #pragma unroll
  for (int d = 0; d < 24; d++) acc[d] = 0.f;
  for (int c = 0; c < 24; c++) {
    float v = (float)vb[(size_t)c * HW_ + e];
    #pragma unroll
    for (int d = 0; d < 24; d++) acc[d] += Ps[d * 24 + c] * v;
  }
  #pragma unroll
  for (int g = 0; g < 3; g++) {
    Pack8 pk;
    #pragma unroll
    for (int u = 0; u < 8; u++) pk.h[u] = __float2bfloat16(acc[g * 8 + u]);
    *(i32x4*)&yt[(size_t)e * 192 + hh * 24 + g * 8] = pk.v;
  }
}

// ---- fused depthwise 3x3 + exact-GELU gate -> transposed bf16 [p][512] -----
__global__ __launch_bounds__(256) void dwgate_kernel(
    const __hip_bfloat16* __restrict__ h, const float* __restrict__ wdw,
    __hip_bfloat16* __restrict__ gt) {
  const int px = blockIdx.x * 64 + (threadIdx.x & 63);
  const int y = blockIdx.y;
  const int c0 = blockIdx.z * 32 + (threadIdx.x >> 6) * 8;
  Pack8 pk;
  #pragma unroll
  for (int u = 0; u < 8; u++) {
    int c = c0 + u;
    float val = 0.f;
    if (c < 510) {
      const __hip_bfloat16* ha = h + (size_t)c * HW_;
      const __hip_bfloat16* hb = h + (size_t)(c + 510) * HW_;
      const float* wa = wdw + c * 9;
      const float* wb = wdw + (c + 510) * 9;
      float s1 = 0.f, s2 = 0.f;
      #pragma unroll
      for (int ky = 0; ky < 3; ky++) {
        int yy = y + ky - 1;
        if (yy < 0 || yy >= 128) continue;
        #pragma unroll
        for (int kx = 0; kx < 3; kx++) {
          int xx = px + kx - 1;
          if (xx < 0 || xx >= 128) continue;
          int o = yy * 128 + xx;
          s1 += (float)ha[o] * wa[ky * 3 + kx];
          s2 += (float)hb[o] * wb[ky * 3 + kx];
        }
      }
      float ge = 0.5f * s1 * (1.f + erff(s1 * 0.70710678118654752f));
      val = ge * s2;
    }
    pk.h[u] = __float2bfloat16(val);
  }
  *(i32x4*)&gt[(size_t)(y * 128 + px) * 512 + c0] = pk.v;
}

// ---------------------------------------------------------------------------
extern "C" void kernel_launch(void* const* d_in, const int* in_sizes, int n_in,
                              void* d_out, int out_size, void* d_ws, size_t ws_size,
                              hipStream_t stream) {
  const float* x     = (const float*)d_in[0];
  const float* temp  = (const float*)d_in[1];
  const float* ln1w  = (const float*)d_in[2];
  const float* ln1b  = (const float*)d_in[3];
  const float* ln2w  = (const float*)d_in[4];
  const float* ln2b  = (const float*)d_in[5];
  const float* wqkv  = (const float*)d_in[6];
  const float* wqkvdw= (const float*)d_in[7];
  const float* wproj = (const float*)d_in[8];
  const float* win   = (const float*)d_in[9];
  const float* wdw   = (const float*)d_in[10];
  const float* wout  = (const float*)d_in[11];
  float* out = (float*)d_out;
  char* ws = (char*)d_ws;

  const int HW = 16384;
  const size_t HWC = (size_t)192 * HW;

  __hip_bfloat16* yt    = (__hip_bfloat16*)(ws + 0);          // 6,291,456 B
  __hip_bfloat16* qkva  = (__hip_bfloat16*)(ws + 6291456);    // 18,874,368
  __hip_bfloat16* qkvb  = (__hip_bfloat16*)(ws + 25165824);   // 18,874,368
  __hip_bfloat16* hbuf  = (__hip_bfloat16*)(ws + 6291456);    // 33,423,360 (overlaps qkva+qkvb)
  float*          xa    = (float*)(ws + 44040192);            // 12,582,912
  __hip_bfloat16* gt    = (__hip_bfloat16*)(ws + 56623104);   // 16,777,216
  __hip_bfloat16* wqkvB = (__hip_bfloat16*)(ws + 73400320);   // 221,184
  __hip_bfloat16* wprojB= (__hip_bfloat16*)(ws + 73621504);   // 73,728
  __hip_bfloat16* winB  = (__hip_bfloat16*)(ws + 73695232);   // 393,216
  __hip_bfloat16* woutB = (__hip_bfloat16*)(ws + 74088448);   // 196,608
  float*          nrm2  = (float*)(ws + 74285056);            // 1,536
  float*          G     = (float*)(ws + 74286592);            // 18,432
  float*          P     = (float*)(ws + 74305024);            // 18,432

  convert_weights<<<768, 256, 0, stream>>>(wqkv, wproj, win, wout,
                                           wqkvB, wprojB, winB, woutB);

  for (int b = 0; b < 4; b++) {
    const float* xb = x + b * HWC;
    float* outb = out + b * HWC;

    hipMemsetAsync(nrm2, 0, 1536 + 18432, stream);   // nrm2 + G contiguous

    // 1. yt = LN1(x_b), transposed bf16
    ln_t_kernel<<<256, 256, 0, stream>>>(xb, ln1w, ln1b, yt);
    // 2. qkva = w_qkv @ y   (576 x 16384), bf16 out
    mfma_gemm<0><<<dim3(9, 128), 256, 0, stream>>>(wqkvB, yt, nullptr, qkva,
                                                   576, HW, 192);
    // 3. qkvb = dwconv3x3(qkva) + fused q,k sum-of-squares
    dw_kernel<<<dim3(2, 32, 576), 256, 0, stream>>>(qkva, wqkvdw, qkvb, nrm2);
    // 4. Gram per head
    gram_kernel<<<dim3(8, 32), 256, 0, stream>>>(qkvb, G);
    // 5. softmax
    softmax_kernel<<<1, 256, 0, stream>>>(G, nrm2, temp, P);
    // 6. yt = (P @ v)^T bf16
    pv_kernel<<<dim3(8, 64), 256, 0, stream>>>(P, qkvb, yt);
    // 7. xa = x_b + w_proj @ pv
    mfma_gemm<1><<<dim3(3, 128), 256, 0, stream>>>(wprojB, yt, xb, xa,
                                                   192, HW, 192);
    // 8. yt = LN2(xa)
    ln_t_kernel<<<256, 256, 0, stream>>>(xa, ln2w, ln2b, yt);
    // 9. hbuf = w_in @ y   (1020 x 16384) bf16
    mfma_gemm<0><<<dim3(16, 128), 256, 0, stream>>>(winB, yt, nullptr, hbuf,
                                                    1020, HW, 192);
    // 10. gt = (gelu(dw(h)_lo) * dw(h)_hi)^T bf16 [p][512], pad zeroed
    dwgate_kernel<<<dim3(2, 128, 16), 256, 0, stream>>>(hbuf, wdw, gt);
    // 11. out_b = xa + w_out @ g   (K=512 padded)
    mfma_gemm<1><<<dim3(3, 128), 256, 0, stream>>>(woutB, gt, xa, outb,
                                                   192, HW, 512);
  }
}

// Round 4
// 838.832 us; speedup vs baseline: 3.3067x; 2.5411x over previous
//
#include <hip/hip_runtime.h>
#include <hip/hip_bf16.h>
#include <math.h>

// ---------------------------------------------------------------------------
// Round 4: determinism/graph-capture hardening of round 3.
//   - NO atomics, NO hipMemsetAsync: all reductions are two-stage
//     write-partials -> deterministic reduce. Every buffer write-before-read.
//   - NO buffer aliasing (hbuf has its own region).
// Perf structure from round 3 kept: vectorized depthwise (8 px/thread),
// MFMA bf16 GEMMs, LDS transpose for gate output.
//
// ws layout (bytes), total 125,160,960 <= 125,589,504 proven in round 1:
//   yt     @ 0            6,291,456   bf16 [p][192]
//   qkva   @ 6,291,456   18,874,368   bf16 [c][p] (576 ch)
//   qkvb   @ 25,165,824  18,874,368   bf16 [c][p]
//   hbuf   @ 44,040,192  33,554,432   bf16 [c][p] (1024 ch padded)
//   xa     @ 77,594,624  12,582,912   fp32 [c][p]
//   gbuf   @ 90,177,536  16,711,680   bf16 [c][p] (510 ch)
//   gt     @ 106,889,216 16,777,216   bf16 [p][512]
//   wqkvB  @ 123,666,432    221,184
//   wprojB @ 123,887,616     73,728
//   winB   @ 123,961,344    393,216   (1024x192, rows >=1020 zero)
//   woutB  @ 124,354,560    196,608   (192x512, cols >=510 zero)
//   nrm2   @ 124,551,168      1,536   fp32 [384]
//   Gpart  @ 124,552,704    589,824   fp32 [32][8][576]
//   P      @ 125,142,528     18,432   fp32 [8][24][24]
// ---------------------------------------------------------------------------

#define HW_ 16384

typedef __attribute__((ext_vector_type(8))) short bf16x8;
typedef __attribute__((ext_vector_type(4))) float f32x4;
typedef __attribute__((ext_vector_type(4))) int i32x4;

union Pack8 { __hip_bfloat16 h[8]; i32x4 v; };

// ---- weight fp32 -> bf16 conversion (with padding) -------------------------
__global__ __launch_bounds__(256) void convert_weights(
    const float* __restrict__ wqkv, const float* __restrict__ wproj,
    const float* __restrict__ win, const float* __restrict__ wout,
    __hip_bfloat16* __restrict__ oq, __hip_bfloat16* __restrict__ op,
    __hip_bfloat16* __restrict__ oi, __hip_bfloat16* __restrict__ oo) {
  const int i = blockIdx.x * 256 + threadIdx.x;
  if (i < 110592) oq[i] = __float2bfloat16(wqkv[i]);            // 576x192
  if (i < 36864)  op[i] = __float2bfloat16(wproj[i]);           // 192x192
  if (i < 196608) {                                             // 1024x192 pad
    int m = i / 192, k = i - m * 192;
    oi[i] = __float2bfloat16(m < 1020 ? win[m * 192 + k] : 0.f);
  }
  if (i < 98304) {                                              // 192x512 pad
    int m = i >> 9, k = i & 511;
    oo[i] = __float2bfloat16(k < 510 ? wout[m * 510 + k] : 0.f);
  }
}

// ---- channel LN -> transposed bf16 output [p][192] -------------------------
__global__ __launch_bounds__(256) void ln_t_kernel(
    const float* __restrict__ x, const float* __restrict__ w,
    const float* __restrict__ bi, __hip_bfloat16* __restrict__ yt) {
  __shared__ float tile[192][65];
  __shared__ float psum[4][64], psq[4][64];
  __shared__ float mu_s[64], inv_s[64];
  const int tid = threadIdx.x;
  const int p0 = blockIdx.x * 64;
  for (int idx = tid; idx < 192 * 64; idx += 256) {
    int c = idx >> 6, p = idx & 63;
    tile[c][p] = x[c * HW_ + p0 + p];
  }
  __syncthreads();
  const int tx = tid & 63, ty = tid >> 6;
  float s = 0.f, s2 = 0.f;
  for (int c = ty * 48; c < ty * 48 + 48; c++) {
    float v = tile[c][tx]; s += v; s2 += v * v;
  }
  psum[ty][tx] = s; psq[ty][tx] = s2;
  __syncthreads();
  if (ty == 0) {
    float ts = psum[0][tx] + psum[1][tx] + psum[2][tx] + psum[3][tx];
    float ts2 = psq[0][tx] + psq[1][tx] + psq[2][tx] + psq[3][tx];
    float mu = ts * (1.f / 192.f);
    float var = ts2 * (1.f / 192.f) - mu * mu;
    mu_s[tx] = mu; inv_s[tx] = rsqrtf(var + 1e-5f);
  }
  __syncthreads();
  for (int idx = tid; idx < 64 * 24; idx += 256) {
    int c8 = idx % 24, p = idx / 24;
    float mu = mu_s[p], inv = inv_s[p];
    Pack8 pk;
    #pragma unroll
    for (int u = 0; u < 8; u++) {
      int c = c8 * 8 + u;
      pk.h[u] = __float2bfloat16((tile[c][p] - mu) * inv * w[c] + bi[c]);
    }
    *(i32x4*)&yt[(size_t)(p0 + p) * 192 + c8 * 8] = pk.v;
  }
}

// ---- MFMA GEMM: D[M][N] = A[M][K] @ B_t[N][K]^T (+res) ---------------------
template <int EPI>
__global__ __launch_bounds__(256) void mfma_gemm(
    const __hip_bfloat16* __restrict__ A, const __hip_bfloat16* __restrict__ B,
    const float* __restrict__ Cres, void* __restrict__ Dout,
    int M, int N, int K) {
  __shared__ __align__(16) __hip_bfloat16 As[64][72];
  __shared__ __align__(16) __hip_bfloat16 Bs[128][72];
  const int tid = threadIdx.x;
  const int wave = tid >> 6, lane = tid & 63;
  const int quad = lane >> 4, lr = lane & 15;
  const int wm = (wave & 1) * 32, wn = (wave >> 1) * 64;
  const int row0 = blockIdx.x * 64, col0 = blockIdx.y * 128;

  f32x4 acc[2][4];
  #pragma unroll
  for (int i = 0; i < 2; i++)
    #pragma unroll
    for (int j = 0; j < 4; j++) acc[i][j] = (f32x4){0.f, 0.f, 0.f, 0.f};

  for (int k0 = 0; k0 < K; k0 += 64) {
    #pragma unroll
    for (int l = 0; l < 2; l++) {
      int t = tid + l * 256;
      int row = t >> 3, ch = t & 7;
      i32x4 v = *(const i32x4*)(A + (size_t)(row0 + row) * K + k0 + ch * 8);
      *(i32x4*)&As[row][ch * 8] = v;
    }
    #pragma unroll
    for (int l = 0; l < 4; l++) {
      int t = tid + l * 256;
      int row = t >> 3, ch = t & 7;
      i32x4 v = *(const i32x4*)(B + (size_t)(col0 + row) * K + k0 + ch * 8);
      *(i32x4*)&Bs[row][ch * 8] = v;
    }
    __syncthreads();
    #pragma unroll
    for (int ks = 0; ks < 2; ks++) {
      bf16x8 a0 = *(const bf16x8*)&As[wm + lr][ks * 32 + quad * 8];
      bf16x8 a1 = *(const bf16x8*)&As[wm + 16 + lr][ks * 32 + quad * 8];
      #pragma unroll
      for (int j = 0; j < 4; j++) {
        bf16x8 bb = *(const bf16x8*)&Bs[wn + j * 16 + lr][ks * 32 + quad * 8];
        acc[0][j] = __builtin_amdgcn_mfma_f32_16x16x32_bf16(a0, bb, acc[0][j], 0, 0, 0);
        acc[1][j] = __builtin_amdgcn_mfma_f32_16x16x32_bf16(a1, bb, acc[1][j], 0, 0, 0);
      }
    }
    __syncthreads();
  }

  #pragma unroll
  for (int i = 0; i < 2; i++) {
    #pragma unroll
    for (int r = 0; r < 4; r++) {
      int gm = row0 + wm + i * 16 + quad * 4 + r;
      if (gm >= M) continue;
      #pragma unroll
      for (int j = 0; j < 4; j++) {
        int gn = col0 + wn + j * 16 + lr;
        size_t idx = (size_t)gm * N + gn;
        if (EPI == 0) {
          ((__hip_bfloat16*)Dout)[idx] = __float2bfloat16(acc[i][j][r]);
        } else {
          ((float*)Dout)[idx] = acc[i][j][r] + Cres[idx];
        }
      }
    }
  }
}

// ---- vectorized depthwise 3x3: 8 px/thread (pure, no reductions) -----------
__global__ __launch_bounds__(256) void dw_kernel(
    const __hip_bfloat16* __restrict__ in, const float* __restrict__ wdw,
    __hip_bfloat16* __restrict__ out) {
  const int c = blockIdx.y;
  const int x8 = threadIdx.x & 15;
  const int y = blockIdx.x * 16 + (threadIdx.x >> 4);
  const __hip_bfloat16* ip = in + (size_t)c * HW_;
  const float* wp = wdw + c * 9;
  float wv[9];
  #pragma unroll
  for (int u = 0; u < 9; u++) wv[u] = wp[u];
  float acc[8];
  #pragma unroll
  for (int j = 0; j < 8; j++) acc[j] = 0.f;
  #pragma unroll
  for (int r = 0; r < 3; r++) {
    int yy = y + r - 1;
    if (yy < 0 || yy >= 128) continue;
    const __hip_bfloat16* rp = ip + yy * 128 + x8 * 8;
    Pack8 mid; mid.v = *(const i32x4*)rp;
    float row[10];
    row[0] = (x8 > 0) ? (float)rp[-1] : 0.f;
    #pragma unroll
    for (int u = 0; u < 8; u++) row[1 + u] = (float)mid.h[u];
    row[9] = (x8 < 15) ? (float)rp[8] : 0.f;
    const float wl = wv[r * 3], wc = wv[r * 3 + 1], wr = wv[r * 3 + 2];
    #pragma unroll
    for (int j = 0; j < 8; j++)
      acc[j] += wl * row[j] + wc * row[j + 1] + wr * row[j + 2];
  }
  Pack8 o;
  #pragma unroll
  for (int j = 0; j < 8; j++) o.h[j] = __float2bfloat16(acc[j]);
  *(i32x4*)(out + (size_t)c * HW_ + y * 128 + x8 * 8) = o.v;
}

// ---- nrm2[r] = sum of squares of qkvb row r (r = 0..383), one block/row ----
__global__ __launch_bounds__(256) void rownorm2_kernel(
    const __hip_bfloat16* __restrict__ qk, float* __restrict__ nrm2) {
  const int r = blockIdx.x;
  const __hip_bfloat16* p = qk + (size_t)r * HW_;
  float s = 0.f;
  for (int i = threadIdx.x * 8; i < HW_; i += 256 * 8) {
    Pack8 v; v.v = *(const i32x4*)(p + i);
    #pragma unroll
    for (int u = 0; u < 8; u++) { float f = (float)v.h[u]; s += f * f; }
  }
  #pragma unroll
  for (int off = 32; off > 0; off >>= 1) s += __shfl_down(s, off, 64);
  __shared__ float wsum[4];
  const int lane = threadIdx.x & 63, wv = threadIdx.x >> 6;
  if (lane == 0) wsum[wv] = s;
  __syncthreads();
  if (threadIdx.x == 0)
    nrm2[r] = wsum[0] + wsum[1] + wsum[2] + wsum[3];
}

// ---- Gram partials: Gpart[chunk][h][d*24+c] = sum_e(chunk) q.k  ------------
__global__ __launch_bounds__(256) void gram_kernel(
    const __hip_bfloat16* __restrict__ qkv, float* __restrict__ Gpart) {
  const int h = blockIdx.x, chunk = blockIdx.y;  // 8 x 32
  const __hip_bfloat16* qb = qkv + (size_t)(h * 24) * HW_;
  const __hip_bfloat16* kb = qkv + (size_t)(192 + h * 24) * HW_;
  __shared__ float qs[24][129], ks[24][129];
  const int tid = threadIdx.x;
  const int p0 = tid, p1 = tid + 256, p2 = tid + 512;
  const int d0 = p0 / 24, c0 = p0 % 24;
  const int d1 = p1 / 24, c1 = p1 % 24;
  const int d2 = (p2 < 576) ? p2 / 24 : 0, c2 = (p2 < 576) ? p2 % 24 : 0;
  float a0 = 0.f, a1 = 0.f, a2 = 0.f;
  const int e_base = chunk * 512;
  for (int e0 = e_base; e0 < e_base + 512; e0 += 128) {
    for (int t = tid; t < 24 * 128; t += 256) {
      int r = t >> 7, col = t & 127;
      qs[r][col] = (float)qb[(size_t)r * HW_ + e0 + col];
      ks[r][col] = (float)kb[(size_t)r * HW_ + e0 + col];
    }
    __syncthreads();
    for (int e = 0; e < 128; e++) {
      a0 += qs[d0][e] * ks[c0][e];
      a1 += qs[d1][e] * ks[c1][e];
      if (p2 < 576) a2 += qs[d2][e] * ks[c2][e];
    }
    __syncthreads();
  }
  float* gp = Gpart + (size_t)(chunk * 8 + h) * 576;
  gp[p0] = a0;
  gp[p1] = a1;
  if (p2 < 576) gp[p2] = a2;
}

// ---- reduce Gpart over chunks + normalize + softmax -> P (one block/head) --
__global__ __launch_bounds__(256) void softmax2_kernel(
    const float* __restrict__ Gpart, const float* __restrict__ nrm2,
    const float* __restrict__ temp, float* __restrict__ P) {
  const int h = blockIdx.x;
  const int tid = threadIdx.x;
  __shared__ float Gs[576];
  __shared__ float nq[24], nk[24];
  for (int t = tid; t < 576; t += 256) {
    float s = 0.f;
    for (int ch = 0; ch < 32; ch++)
      s += Gpart[(size_t)(ch * 8 + h) * 576 + t];
    Gs[t] = s;
  }
  if (tid < 24) {
    nq[tid] = fmaxf(sqrtf(nrm2[h * 24 + tid]), 1e-12f);
    nk[tid] = fmaxf(sqrtf(nrm2[192 + h * 24 + tid]), 1e-12f);
  }
  __syncthreads();
  if (tid < 24) {
    const int d = tid;
    const float tp = temp[h];
    float row[24], mx = -1e30f;
    #pragma unroll
    for (int c = 0; c < 24; c++) {
      float v = Gs[d * 24 + c] * tp / (nq[d] * nk[c]);
      row[c] = v; mx = fmaxf(mx, v);
    }
    float s = 0.f;
    #pragma unroll
    for (int c = 0; c < 24; c++) { float e = expf(row[c] - mx); row[c] = e; s += e; }
    const float inv = 1.f / s;
    #pragma unroll
    for (int c = 0; c < 24; c++) P[h * 576 + d * 24 + c] = row[c] * inv;
  }
}

// ---- out_t[e][h*24+d] = sum_c P[h,d,c]*v[h,c,e]  (bf16 transposed out) -----
__global__ __launch_bounds__(256) void pv_kernel(
    const float* __restrict__ P, const __hip_bfloat16* __restrict__ qkv,
    __hip_bfloat16* __restrict__ yt) {
  const int hh = blockIdx.x;
  const int e = blockIdx.y * 256 + threadIdx.x;
  __shared__ float Ps[576];
  for (int t = threadIdx.x; t < 576; t += 256) Ps[t] = P[hh * 576 + t];
  __syncthreads();
  const __hip_bfloat16* vb = qkv + (size_t)(384 + hh * 24) * HW_;
  float acc[24];
  #pragma unroll
  for (int d = 0; d < 24; d++) acc[d] = 0.f;
  for (int c = 0; c < 24; c++) {
    float v = (float)vb[(size_t)c * HW_ + e];
    #pragma unroll
    for (int d = 0; d < 24; d++) acc[d] += Ps[d * 24 + c] * v;
  }
  #pragma unroll
  for (int g = 0; g < 3; g++) {
    Pack8 pk;
    #pragma unroll
    for (int u = 0; u < 8; u++) pk.h[u] = __float2bfloat16(acc[g * 8 + u]);
    *(i32x4*)&yt[(size_t)e * 192 + hh * 24 + g * 8] = pk.v;
  }
}

// ---- vectorized FFN depthwise + GELU gate -> gbuf [c][p] bf16 --------------
__global__ __launch_bounds__(256) void dwg_kernel(
    const __hip_bfloat16* __restrict__ h, const float* __restrict__ wdw,
    __hip_bfloat16* __restrict__ g) {
  const int c = blockIdx.y;      // 0..509
  const int x8 = threadIdx.x & 15;
  const int y = blockIdx.x * 16 + (threadIdx.x >> 4);
  const __hip_bfloat16* ha = h + (size_t)c * HW_;
  const __hip_bfloat16* hb = h + (size_t)(c + 510) * HW_;
  const float* wa = wdw + c * 9;
  const float* wb = wdw + (c + 510) * 9;
  float wva[9], wvb[9];
  #pragma unroll
  for (int u = 0; u < 9; u++) { wva[u] = wa[u]; wvb[u] = wb[u]; }
  float s1[8], s2[8];
  #pragma unroll
  for (int j = 0; j < 8; j++) { s1[j] = 0.f; s2[j] = 0.f; }
  #pragma unroll
  for (int r = 0; r < 3; r++) {
    int yy = y + r - 1;
    if (yy < 0 || yy >= 128) continue;
    const int off = yy * 128 + x8 * 8;
    Pack8 ma; ma.v = *(const i32x4*)(ha + off);
    Pack8 mb; mb.v = *(const i32x4*)(hb + off);
    float rowa[10], rowb[10];
    rowa[0] = (x8 > 0) ? (float)ha[off - 1] : 0.f;
    rowb[0] = (x8 > 0) ? (float)hb[off - 1] : 0.f;
    #pragma unroll
    for (int u = 0; u < 8; u++) { rowa[1 + u] = (float)ma.h[u]; rowb[1 + u] = (float)mb.h[u]; }
    rowa[9] = (x8 < 15) ? (float)ha[off + 8] : 0.f;
    rowb[9] = (x8 < 15) ? (float)hb[off + 8] : 0.f;
    const float al = wva[r * 3], ac = wva[r * 3 + 1], ar = wva[r * 3 + 2];
    const float bl = wvb[r * 3], bc = wvb[r * 3 + 1], br = wvb[r * 3 + 2];
    #pragma unroll
    for (int j = 0; j < 8; j++) {
      s1[j] += al * rowa[j] + ac * rowa[j + 1] + ar * rowa[j + 2];
      s2[j] += bl * rowb[j] + bc * rowb[j + 1] + br * rowb[j + 2];
    }
  }
  Pack8 o;
  #pragma unroll
  for (int j = 0; j < 8; j++) {
    float ge = 0.5f * s1[j] * (1.f + erff(s1[j] * 0.70710678118654752f));
    o.h[j] = __float2bfloat16(ge * s2[j]);
  }
  *(i32x4*)(g + (size_t)c * HW_ + y * 128 + x8 * 8) = o.v;
}

// ---- transpose gbuf [510][16384] -> gt [16384][512] (pad c=510,511 zero) ---
__global__ __launch_bounds__(256) void transpose_kernel(
    const __hip_bfloat16* __restrict__ src, __hip_bfloat16* __restrict__ dst) {
  __shared__ __hip_bfloat16 t[64][65];
  const int p0 = blockIdx.x * 64, c0 = blockIdx.y * 64;
  for (int idx = threadIdx.x; idx < 512; idx += 256) {
    int cl = idx >> 3, pj = idx & 7;
    int c = c0 + cl;
    Pack8 v;
    if (c < 510) v.v = *(const i32x4*)(src + (size_t)c * HW_ + p0 + pj * 8);
    else {
      #pragma unroll
      for (int u = 0; u < 8; u++) v.h[u] = __float2bfloat16(0.f);
    }
    #pragma unroll
    for (int u = 0; u < 8; u++) t[cl][pj * 8 + u] = v.h[u];
  }
  __syncthreads();
  for (int idx = threadIdx.x; idx < 512; idx += 256) {
    int pl = idx >> 3, cj = idx & 7;
    Pack8 o;
    #pragma unroll
    for (int u = 0; u < 8; u++) o.h[u] = t[cj * 8 + u][pl];
    *(i32x4*)(dst + (size_t)(p0 + pl) * 512 + c0 + cj * 8) = o.v;
  }
}

// ---------------------------------------------------------------------------
extern "C" void kernel_launch(void* const* d_in, const int* in_sizes, int n_in,
                              void* d_out, int out_size, void* d_ws, size_t ws_size,
                              hipStream_t stream) {
  const float* x     = (const float*)d_in[0];
  const float* temp  = (const float*)d_in[1];
  const float* ln1w  = (const float*)d_in[2];
  const float* ln1b  = (const float*)d_in[3];
  const float* ln2w  = (const float*)d_in[4];
  const float* ln2b  = (const float*)d_in[5];
  const float* wqkv  = (const float*)d_in[6];
  const float* wqkvdw= (const float*)d_in[7];
  const float* wproj = (const float*)d_in[8];
  const float* win   = (const float*)d_in[9];
  const float* wdw   = (const float*)d_in[10];
  const float* wout  = (const float*)d_in[11];
  float* out = (float*)d_out;
  char* ws = (char*)d_ws;

  const int HW = 16384;
  const size_t HWC = (size_t)192 * HW;

  __hip_bfloat16* yt    = (__hip_bfloat16*)(ws + 0);
  __hip_bfloat16* qkva  = (__hip_bfloat16*)(ws + 6291456);
  __hip_bfloat16* qkvb  = (__hip_bfloat16*)(ws + 25165824);
  __hip_bfloat16* hbuf  = (__hip_bfloat16*)(ws + 44040192);
  float*          xa    = (float*)(ws + 77594624);
  __hip_bfloat16* gbuf  = (__hip_bfloat16*)(ws + 90177536);
  __hip_bfloat16* gt    = (__hip_bfloat16*)(ws + 106889216);
  __hip_bfloat16* wqkvB = (__hip_bfloat16*)(ws + 123666432);
  __hip_bfloat16* wprojB= (__hip_bfloat16*)(ws + 123887616);
  __hip_bfloat16* winB  = (__hip_bfloat16*)(ws + 123961344);
  __hip_bfloat16* woutB = (__hip_bfloat16*)(ws + 124354560);
  float*          nrm2  = (float*)(ws + 124551168);
  float*          Gpart = (float*)(ws + 124552704);
  float*          P     = (float*)(ws + 125142528);

  convert_weights<<<768, 256, 0, stream>>>(wqkv, wproj, win, wout,
                                           wqkvB, wprojB, winB, woutB);

  for (int b = 0; b < 4; b++) {
    const float* xb = x + b * HWC;
    float* outb = out + b * HWC;

    // 1. yt = LN1(x_b), transposed bf16
    ln_t_kernel<<<256, 256, 0, stream>>>(xb, ln1w, ln1b, yt);
    // 2. qkva = w_qkv @ y   (576 x 16384), bf16 out
    mfma_gemm<0><<<dim3(9, 128), 256, 0, stream>>>(wqkvB, yt, nullptr, qkva,
                                                   576, HW, 192);
    // 3. qkvb = dwconv3x3(qkva)
    dw_kernel<<<dim3(8, 576), 256, 0, stream>>>(qkva, wqkvdw, qkvb);
    // 4. nrm2[r] = sum of squares of q,k rows (deterministic, one store/row)
    rownorm2_kernel<<<384, 256, 0, stream>>>(qkvb, nrm2);
    // 5. Gram partials (pure writes, no atomics)
    gram_kernel<<<dim3(8, 32), 256, 0, stream>>>(qkvb, Gpart);
    // 6. P = softmax(reduce(Gpart) * temp / (|q||k|))
    softmax2_kernel<<<8, 256, 0, stream>>>(Gpart, nrm2, temp, P);
    // 7. yt = (P @ v)^T bf16
    pv_kernel<<<dim3(8, 64), 256, 0, stream>>>(P, qkvb, yt);
    // 8. xa = x_b + w_proj @ pv
    mfma_gemm<1><<<dim3(3, 128), 256, 0, stream>>>(wprojB, yt, xb, xa,
                                                   192, HW, 192);
    // 9. yt = LN2(xa)
    ln_t_kernel<<<256, 256, 0, stream>>>(xa, ln2w, ln2b, yt);
    // 10. hbuf = w_in @ y   (1020 x 16384) bf16
    mfma_gemm<0><<<dim3(16, 128), 256, 0, stream>>>(winB, yt, nullptr, hbuf,
                                                    1020, HW, 192);
    // 11. gbuf = gelu(dw(h)_lo) * dw(h)_hi   [c][p]
    dwg_kernel<<<dim3(8, 510), 256, 0, stream>>>(hbuf, wdw, gbuf);
    // 12. gt = gbuf^T  [p][512] (c pad zeroed)
    transpose_kernel<<<dim3(256, 8), 256, 0, stream>>>(gbuf, gt);
    // 13. out_b = xa + w_out @ g   (K=512 padded)
    mfma_gemm<1><<<dim3(3, 128), 256, 0, stream>>>(woutB, gt, xa, outb,
                                                   192, HW, 512);
  }
}

// Round 5
// 706.730 us; speedup vs baseline: 3.9248x; 1.1869x over previous
//
#include <hip/hip_runtime.h>
#include <hip/hip_bf16.h>
#include <math.h>

// ---------------------------------------------------------------------------
// Round 5: MFMA-based Gram (split-K, 32x32x16 bf16, no LDS staging) replacing
// the latency-bound VALU gram (47us -> target ~8us). ln_t global loads
// vectorized to float4. Everything else identical to round 4 (which passed
// all tripwires: no atomics, no memsets, no aliasing).
//
// ws layout (bytes), total 125,160,960:
//   yt     @ 0            6,291,456   bf16 [p][192]
//   qkva   @ 6,291,456   18,874,368   bf16 [c][p] (576 ch)
//   qkvb   @ 25,165,824  18,874,368   bf16 [c][p]
//   hbuf   @ 44,040,192  33,554,432   bf16 [c][p] (1024 ch padded)
//   xa     @ 77,594,624  12,582,912   fp32 [c][p]
//   gbuf   @ 90,177,536  16,711,680   bf16 [c][p] (510 ch)
//   gt     @ 106,889,216 16,777,216   bf16 [p][512]
//   wqkvB  @ 123,666,432    221,184
//   wprojB @ 123,887,616     73,728
//   winB   @ 123,961,344    393,216   (1024x192, rows >=1020 zero)
//   woutB  @ 124,354,560    196,608   (192x512, cols >=510 zero)
//   nrm2   @ 124,551,168      1,536   fp32 [384]
//   Gpart  @ 124,552,704    589,824   fp32 [32][8][576]
//   P      @ 125,142,528     18,432   fp32 [8][24][24]
// ---------------------------------------------------------------------------

#define HW_ 16384

typedef __attribute__((ext_vector_type(8))) short bf16x8;
typedef __attribute__((ext_vector_type(4))) float f32x4;
typedef __attribute__((ext_vector_type(16))) float f32x16;
typedef __attribute__((ext_vector_type(4))) int i32x4;

union Pack8 { __hip_bfloat16 h[8]; i32x4 v; };

// ---- weight fp32 -> bf16 conversion (with padding) -------------------------
__global__ __launch_bounds__(256) void convert_weights(
    const float* __restrict__ wqkv, const float* __restrict__ wproj,
    const float* __restrict__ win, const float* __restrict__ wout,
    __hip_bfloat16* __restrict__ oq, __hip_bfloat16* __restrict__ op,
    __hip_bfloat16* __restrict__ oi, __hip_bfloat16* __restrict__ oo) {
  const int i = blockIdx.x * 256 + threadIdx.x;
  if (i < 110592) oq[i] = __float2bfloat16(wqkv[i]);            // 576x192
  if (i < 36864)  op[i] = __float2bfloat16(wproj[i]);           // 192x192
  if (i < 196608) {                                             // 1024x192 pad
    int m = i / 192, k = i - m * 192;
    oi[i] = __float2bfloat16(m < 1020 ? win[m * 192 + k] : 0.f);
  }
  if (i < 98304) {                                              // 192x512 pad
    int m = i >> 9, k = i & 511;
    oo[i] = __float2bfloat16(k < 510 ? wout[m * 510 + k] : 0.f);
  }
}

// ---- channel LN -> transposed bf16 output [p][192] -------------------------
__global__ __launch_bounds__(256) void ln_t_kernel(
    const float* __restrict__ x, const float* __restrict__ w,
    const float* __restrict__ bi, __hip_bfloat16* __restrict__ yt) {
  __shared__ float tile[192][68];   // stride 68: 16B-aligned float4 slots
  __shared__ float psum[4][64], psq[4][64];
  __shared__ float mu_s[64], inv_s[64];
  const int tid = threadIdx.x;
  const int p0 = blockIdx.x * 64;
  // vectorized load: 192*16 float4s
  for (int idx = tid; idx < 192 * 16; idx += 256) {
    int c = idx >> 4, p4 = idx & 15;
    f32x4 v = *(const f32x4*)(x + (size_t)c * HW_ + p0 + p4 * 4);
    *(f32x4*)&tile[c][p4 * 4] = v;
  }
  __syncthreads();
  const int tx = tid & 63, ty = tid >> 6;
  float s = 0.f, s2 = 0.f;
  for (int c = ty * 48; c < ty * 48 + 48; c++) {
    float v = tile[c][tx]; s += v; s2 += v * v;
  }
  psum[ty][tx] = s; psq[ty][tx] = s2;
  __syncthreads();
  if (ty == 0) {
    float ts = psum[0][tx] + psum[1][tx] + psum[2][tx] + psum[3][tx];
    float ts2 = psq[0][tx] + psq[1][tx] + psq[2][tx] + psq[3][tx];
    float mu = ts * (1.f / 192.f);
    float var = ts2 * (1.f / 192.f) - mu * mu;
    mu_s[tx] = mu; inv_s[tx] = rsqrtf(var + 1e-5f);
  }
  __syncthreads();
  for (int idx = tid; idx < 64 * 24; idx += 256) {
    int c8 = idx % 24, p = idx / 24;
    float mu = mu_s[p], inv = inv_s[p];
    Pack8 pk;
    #pragma unroll
    for (int u = 0; u < 8; u++) {
      int c = c8 * 8 + u;
      pk.h[u] = __float2bfloat16((tile[c][p] - mu) * inv * w[c] + bi[c]);
    }
    *(i32x4*)&yt[(size_t)(p0 + p) * 192 + c8 * 8] = pk.v;
  }
}

// ---- MFMA GEMM: D[M][N] = A[M][K] @ B_t[N][K]^T (+res) ---------------------
template <int EPI>
__global__ __launch_bounds__(256) void mfma_gemm(
    const __hip_bfloat16* __restrict__ A, const __hip_bfloat16* __restrict__ B,
    const float* __restrict__ Cres, void* __restrict__ Dout,
    int M, int N, int K) {
  __shared__ __align__(16) __hip_bfloat16 As[64][72];
  __shared__ __align__(16) __hip_bfloat16 Bs[128][72];
  const int tid = threadIdx.x;
  const int wave = tid >> 6, lane = tid & 63;
  const int quad = lane >> 4, lr = lane & 15;
  const int wm = (wave & 1) * 32, wn = (wave >> 1) * 64;
  const int row0 = blockIdx.x * 64, col0 = blockIdx.y * 128;

  f32x4 acc[2][4];
  #pragma unroll
  for (int i = 0; i < 2; i++)
    #pragma unroll
    for (int j = 0; j < 4; j++) acc[i][j] = (f32x4){0.f, 0.f, 0.f, 0.f};

  for (int k0 = 0; k0 < K; k0 += 64) {
    #pragma unroll
    for (int l = 0; l < 2; l++) {
      int t = tid + l * 256;
      int row = t >> 3, ch = t & 7;
      i32x4 v = *(const i32x4*)(A + (size_t)(row0 + row) * K + k0 + ch * 8);
      *(i32x4*)&As[row][ch * 8] = v;
    }
    #pragma unroll
    for (int l = 0; l < 4; l++) {
      int t = tid + l * 256;
      int row = t >> 3, ch = t & 7;
      i32x4 v = *(const i32x4*)(B + (size_t)(col0 + row) * K + k0 + ch * 8);
      *(i32x4*)&Bs[row][ch * 8] = v;
    }
    __syncthreads();
    #pragma unroll
    for (int ks = 0; ks < 2; ks++) {
      bf16x8 a0 = *(const bf16x8*)&As[wm + lr][ks * 32 + quad * 8];
      bf16x8 a1 = *(const bf16x8*)&As[wm + 16 + lr][ks * 32 + quad * 8];
      #pragma unroll
      for (int j = 0; j < 4; j++) {
        bf16x8 bb = *(const bf16x8*)&Bs[wn + j * 16 + lr][ks * 32 + quad * 8];
        acc[0][j] = __builtin_amdgcn_mfma_f32_16x16x32_bf16(a0, bb, acc[0][j], 0, 0, 0);
        acc[1][j] = __builtin_amdgcn_mfma_f32_16x16x32_bf16(a1, bb, acc[1][j], 0, 0, 0);
      }
    }
    __syncthreads();
  }

  #pragma unroll
  for (int i = 0; i < 2; i++) {
    #pragma unroll
    for (int r = 0; r < 4; r++) {
      int gm = row0 + wm + i * 16 + quad * 4 + r;
      if (gm >= M) continue;
      #pragma unroll
      for (int j = 0; j < 4; j++) {
        int gn = col0 + wn + j * 16 + lr;
        size_t idx = (size_t)gm * N + gn;
        if (EPI == 0) {
          ((__hip_bfloat16*)Dout)[idx] = __float2bfloat16(acc[i][j][r]);
        } else {
          ((float*)Dout)[idx] = acc[i][j][r] + Cres[idx];
        }
      }
    }
  }
}

// ---- vectorized depthwise 3x3: 8 px/thread (pure, no reductions) -----------
__global__ __launch_bounds__(256) void dw_kernel(
    const __hip_bfloat16* __restrict__ in, const float* __restrict__ wdw,
    __hip_bfloat16* __restrict__ out) {
  const int c = blockIdx.y;
  const int x8 = threadIdx.x & 15;
  const int y = blockIdx.x * 16 + (threadIdx.x >> 4);
  const __hip_bfloat16* ip = in + (size_t)c * HW_;
  const float* wp = wdw + c * 9;
  float wv[9];
  #pragma unroll
  for (int u = 0; u < 9; u++) wv[u] = wp[u];
  float acc[8];
  #pragma unroll
  for (int j = 0; j < 8; j++) acc[j] = 0.f;
  #pragma unroll
  for (int r = 0; r < 3; r++) {
    int yy = y + r - 1;
    if (yy < 0 || yy >= 128) continue;
    const __hip_bfloat16* rp = ip + yy * 128 + x8 * 8;
    Pack8 mid; mid.v = *(const i32x4*)rp;
    float row[10];
    row[0] = (x8 > 0) ? (float)rp[-1] : 0.f;
    #pragma unroll
    for (int u = 0; u < 8; u++) row[1 + u] = (float)mid.h[u];
    row[9] = (x8 < 15) ? (float)rp[8] : 0.f;
    const float wl = wv[r * 3], wc = wv[r * 3 + 1], wr = wv[r * 3 + 2];
    #pragma unroll
    for (int j = 0; j < 8; j++)
      acc[j] += wl * row[j] + wc * row[j + 1] + wr * row[j + 2];
  }
  Pack8 o;
  #pragma unroll
  for (int j = 0; j < 8; j++) o.h[j] = __float2bfloat16(acc[j]);
  *(i32x4*)(out + (size_t)c * HW_ + y * 128 + x8 * 8) = o.v;
}

// ---- nrm2[r] = sum of squares of qkvb row r (r = 0..383), one block/row ----
__global__ __launch_bounds__(256) void rownorm2_kernel(
    const __hip_bfloat16* __restrict__ qk, float* __restrict__ nrm2) {
  const int r = blockIdx.x;
  const __hip_bfloat16* p = qk + (size_t)r * HW_;
  float s = 0.f;
  for (int i = threadIdx.x * 8; i < HW_; i += 256 * 8) {
    Pack8 v; v.v = *(const i32x4*)(p + i);
    #pragma unroll
    for (int u = 0; u < 8; u++) { float f = (float)v.h[u]; s += f * f; }
  }
  #pragma unroll
  for (int off = 32; off > 0; off >>= 1) s += __shfl_down(s, off, 64);
  __shared__ float wsum[4];
  const int lane = threadIdx.x & 63, wv = threadIdx.x >> 6;
  if (lane == 0) wsum[wv] = s;
  __syncthreads();
  if (threadIdx.x == 0)
    nrm2[r] = wsum[0] + wsum[1] + wsum[2] + wsum[3];
}

// ---- MFMA Gram partials: Gpart[chunk][h][d*24+c] = sum_e(chunk) q.k --------
// grid (8 heads, 32 chunks), 256 thr = 4 waves. Each wave: one 32x32 tile
// (24x24 used) over a 128-wide e-slice via 8x mfma_32x32x16_bf16 with direct
// 16B global fragment loads. Cross-wave reduce in LDS, one store per entry.
__global__ __launch_bounds__(256) void gram_kernel(
    const __hip_bfloat16* __restrict__ qkv, float* __restrict__ Gpart) {
  const int h = blockIdx.x, chunk = blockIdx.y;
  const int tid = threadIdx.x;
  const int w = tid >> 6, lane = tid & 63;
  const int m = lane & 31;          // tile row (q d) / col (k c); >=24 ignored
  const int khalf = lane >> 5;      // k-offset 0 / 8
  const __hip_bfloat16* qb = qkv + (size_t)(h * 24) * HW_;       // rows m<32 stay < 576
  const __hip_bfloat16* kb = qkv + (size_t)(192 + h * 24) * HW_;
  f32x16 acc;
  #pragma unroll
  for (int i = 0; i < 16; i++) acc[i] = 0.f;
  const int e0 = chunk * 512 + w * 128;
  #pragma unroll
  for (int j = 0; j < 8; j++) {
    const int k0 = e0 + j * 16 + khalf * 8;
    bf16x8 a = *(const bf16x8*)(qb + (size_t)m * HW_ + k0);
    bf16x8 bfr = *(const bf16x8*)(kb + (size_t)m * HW_ + k0);
    acc = __builtin_amdgcn_mfma_f32_32x32x16_bf16(a, bfr, acc, 0, 0, 0);
  }
  __shared__ float gs[4][576];
  #pragma unroll
  for (int r = 0; r < 16; r++) {
    int row = (r & 3) + 8 * (r >> 2) + 4 * khalf;
    if (row < 24 && m < 24) gs[w][row * 24 + m] = acc[r];
  }
  __syncthreads();
  float* gp = Gpart + (size_t)(chunk * 8 + h) * 576;
  for (int t = tid; t < 576; t += 256)
    gp[t] = gs[0][t] + gs[1][t] + gs[2][t] + gs[3][t];
}

// ---- reduce Gpart over chunks + normalize + softmax -> P (one block/head) --
__global__ __launch_bounds__(256) void softmax2_kernel(
    const float* __restrict__ Gpart, const float* __restrict__ nrm2,
    const float* __restrict__ temp, float* __restrict__ P) {
  const int h = blockIdx.x;
  const int tid = threadIdx.x;
  __shared__ float Gs[576];
  __shared__ float nq[24], nk[24];
  for (int t = tid; t < 576; t += 256) {
    float s = 0.f;
    for (int ch = 0; ch < 32; ch++)
      s += Gpart[(size_t)(ch * 8 + h) * 576 + t];
    Gs[t] = s;
  }
  if (tid < 24) {
    nq[tid] = fmaxf(sqrtf(nrm2[h * 24 + tid]), 1e-12f);
    nk[tid] = fmaxf(sqrtf(nrm2[192 + h * 24 + tid]), 1e-12f);
  }
  __syncthreads();
  if (tid < 24) {
    const int d = tid;
    const float tp = temp[h];
    float row[24], mx = -1e30f;
    #pragma unroll
    for (int c = 0; c < 24; c++) {
      float v = Gs[d * 24 + c] * tp / (nq[d] * nk[c]);
      row[c] = v; mx = fmaxf(mx, v);
    }
    float s = 0.f;
    #pragma unroll
    for (int c = 0; c < 24; c++) { float e = expf(row[c] - mx); row[c] = e; s += e; }
    const float inv = 1.f / s;
    #pragma unroll
    for (int c = 0; c < 24; c++) P[h * 576 + d * 24 + c] = row[c] * inv;
  }
}

// ---- out_t[e][h*24+d] = sum_c P[h,d,c]*v[h,c,e]  (bf16 transposed out) -----
__global__ __launch_bounds__(256) void pv_kernel(
    const float* __restrict__ P, const __hip_bfloat16* __restrict__ qkv,
    __hip_bfloat16* __restrict__ yt) {
  const int hh = blockIdx.x;
  const int e = blockIdx.y * 256 + threadIdx.x;
  __shared__ float Ps[576];
  for (int t = threadIdx.x; t < 576; t += 256) Ps[t] = P[hh * 576 + t];
  __syncthreads();
  const __hip_bfloat16* vb = qkv + (size_t)(384 + hh * 24) * HW_;
  float acc[24];
  #pragma unroll
  for (int d = 0; d < 24; d++) acc[d] = 0.f;
  for (int c = 0; c < 24; c++) {
    float v = (float)vb[(size_t)c * HW_ + e];
    #pragma unroll
    for (int d = 0; d < 24; d++) acc[d] += Ps[d * 24 + c] * v;
  }
  #pragma unroll
  for (int g = 0; g < 3; g++) {
    Pack8 pk;
    #pragma unroll
    for (int u = 0; u < 8; u++) pk.h[u] = __float2bfloat16(acc[g * 8 + u]);
    *(i32x4*)&yt[(size_t)e * 192 + hh * 24 + g * 8] = pk.v;
  }
}

// ---- vectorized FFN depthwise + GELU gate -> gbuf [c][p] bf16 --------------
__global__ __launch_bounds__(256) void dwg_kernel(
    const __hip_bfloat16* __restrict__ h, const float* __restrict__ wdw,
    __hip_bfloat16* __restrict__ g) {
  const int c = blockIdx.y;      // 0..509
  const int x8 = threadIdx.x & 15;
  const int y = blockIdx.x * 16 + (threadIdx.x >> 4);
  const __hip_bfloat16* ha = h + (size_t)c * HW_;
  const __hip_bfloat16* hb = h + (size_t)(c + 510) * HW_;
  const float* wa = wdw + c * 9;
  const float* wb = wdw + (c + 510) * 9;
  float wva[9], wvb[9];
  #pragma unroll
  for (int u = 0; u < 9; u++) { wva[u] = wa[u]; wvb[u] = wb[u]; }
  float s1[8], s2[8];
  #pragma unroll
  for (int j = 0; j < 8; j++) { s1[j] = 0.f; s2[j] = 0.f; }
  #pragma unroll
  for (int r = 0; r < 3; r++) {
    int yy = y + r - 1;
    if (yy < 0 || yy >= 128) continue;
    const int off = yy * 128 + x8 * 8;
    Pack8 ma; ma.v = *(const i32x4*)(ha + off);
    Pack8 mb; mb.v = *(const i32x4*)(hb + off);
    float rowa[10], rowb[10];
    rowa[0] = (x8 > 0) ? (float)ha[off - 1] : 0.f;
    rowb[0] = (x8 > 0) ? (float)hb[off - 1] : 0.f;
    #pragma unroll
    for (int u = 0; u < 8; u++) { rowa[1 + u] = (float)ma.h[u]; rowb[1 + u] = (float)mb.h[u]; }
    rowa[9] = (x8 < 15) ? (float)ha[off + 8] : 0.f;
    rowb[9] = (x8 < 15) ? (float)hb[off + 8] : 0.f;
    const float al = wva[r * 3], ac = wva[r * 3 + 1], ar = wva[r * 3 + 2];
    const float bl = wvb[r * 3], bc = wvb[r * 3 + 1], br = wvb[r * 3 + 2];
    #pragma unroll
    for (int j = 0; j < 8; j++) {
      s1[j] += al * rowa[j] + ac * rowa[j + 1] + ar * rowa[j + 2];
      s2[j] += bl * rowb[j] + bc * rowb[j + 1] + br * rowb[j + 2];
    }
  }
  Pack8 o;
  #pragma unroll
  for (int j = 0; j < 8; j++) {
    float ge = 0.5f * s1[j] * (1.f + erff(s1[j] * 0.70710678118654752f));
    o.h[j] = __float2bfloat16(ge * s2[j]);
  }
  *(i32x4*)(g + (size_t)c * HW_ + y * 128 + x8 * 8) = o.v;
}

// ---- transpose gbuf [510][16384] -> gt [16384][512] (pad c=510,511 zero) ---
__global__ __launch_bounds__(256) void transpose_kernel(
    const __hip_bfloat16* __restrict__ src, __hip_bfloat16* __restrict__ dst) {
  __shared__ __hip_bfloat16 t[64][65];
  const int p0 = blockIdx.x * 64, c0 = blockIdx.y * 64;
  for (int idx = threadIdx.x; idx < 512; idx += 256) {
    int cl = idx >> 3, pj = idx & 7;
    int c = c0 + cl;
    Pack8 v;
    if (c < 510) v.v = *(const i32x4*)(src + (size_t)c * HW_ + p0 + pj * 8);
    else {
      #pragma unroll
      for (int u = 0; u < 8; u++) v.h[u] = __float2bfloat16(0.f);
    }
    #pragma unroll
    for (int u = 0; u < 8; u++) t[cl][pj * 8 + u] = v.h[u];
  }
  __syncthreads();
  for (int idx = threadIdx.x; idx < 512; idx += 256) {
    int pl = idx >> 3, cj = idx & 7;
    Pack8 o;
    #pragma unroll
    for (int u = 0; u < 8; u++) o.h[u] = t[cj * 8 + u][pl];
    *(i32x4*)(dst + (size_t)(p0 + pl) * 512 + c0 + cj * 8) = o.v;
  }
}

// ---------------------------------------------------------------------------
extern "C" void kernel_launch(void* const* d_in, const int* in_sizes, int n_in,
                              void* d_out, int out_size, void* d_ws, size_t ws_size,
                              hipStream_t stream) {
  const float* x     = (const float*)d_in[0];
  const float* temp  = (const float*)d_in[1];
  const float* ln1w  = (const float*)d_in[2];
  const float* ln1b  = (const float*)d_in[3];
  const float* ln2w  = (const float*)d_in[4];
  const float* ln2b  = (const float*)d_in[5];
  const float* wqkv  = (const float*)d_in[6];
  const float* wqkvdw= (const float*)d_in[7];
  const float* wproj = (const float*)d_in[8];
  const float* win   = (const float*)d_in[9];
  const float* wdw   = (const float*)d_in[10];
  const float* wout  = (const float*)d_in[11];
  float* out = (float*)d_out;
  char* ws = (char*)d_ws;

  const int HW = 16384;
  const size_t HWC = (size_t)192 * HW;

  __hip_bfloat16* yt    = (__hip_bfloat16*)(ws + 0);
  __hip_bfloat16* qkva  = (__hip_bfloat16*)(ws + 6291456);
  __hip_bfloat16* qkvb  = (__hip_bfloat16*)(ws + 25165824);
  __hip_bfloat16* hbuf  = (__hip_bfloat16*)(ws + 44040192);
  float*          xa    = (float*)(ws + 77594624);
  __hip_bfloat16* gbuf  = (__hip_bfloat16*)(ws + 90177536);
  __hip_bfloat16* gt    = (__hip_bfloat16*)(ws + 106889216);
  __hip_bfloat16* wqkvB = (__hip_bfloat16*)(ws + 123666432);
  __hip_bfloat16* wprojB= (__hip_bfloat16*)(ws + 123887616);
  __hip_bfloat16* winB  = (__hip_bfloat16*)(ws + 123961344);
  __hip_bfloat16* woutB = (__hip_bfloat16*)(ws + 124354560);
  float*          nrm2  = (float*)(ws + 124551168);
  float*          Gpart = (float*)(ws + 124552704);
  float*          P     = (float*)(ws + 125142528);

  convert_weights<<<768, 256, 0, stream>>>(wqkv, wproj, win, wout,
                                           wqkvB, wprojB, winB, woutB);

  for (int b = 0; b < 4; b++) {
    const float* xb = x + b * HWC;
    float* outb = out + b * HWC;

    // 1. yt = LN1(x_b), transposed bf16
    ln_t_kernel<<<256, 256, 0, stream>>>(xb, ln1w, ln1b, yt);
    // 2. qkva = w_qkv @ y   (576 x 16384), bf16 out
    mfma_gemm<0><<<dim3(9, 128), 256, 0, stream>>>(wqkvB, yt, nullptr, qkva,
                                                   576, HW, 192);
    // 3. qkvb = dwconv3x3(qkva)
    dw_kernel<<<dim3(8, 576), 256, 0, stream>>>(qkva, wqkvdw, qkvb);
    // 4. nrm2[r] = sum of squares of q,k rows
    rownorm2_kernel<<<384, 256, 0, stream>>>(qkvb, nrm2);
    // 5. Gram partials via MFMA (pure writes)
    gram_kernel<<<dim3(8, 32), 256, 0, stream>>>(qkvb, Gpart);
    // 6. P = softmax(reduce(Gpart) * temp / (|q||k|))
    softmax2_kernel<<<8, 256, 0, stream>>>(Gpart, nrm2, temp, P);
    // 7. yt = (P @ v)^T bf16
    pv_kernel<<<dim3(8, 64), 256, 0, stream>>>(P, qkvb, yt);
    // 8. xa = x_b + w_proj @ pv
    mfma_gemm<1><<<dim3(3, 128), 256, 0, stream>>>(wprojB, yt, xb, xa,
                                                   192, HW, 192);
    // 9. yt = LN2(xa)
    ln_t_kernel<<<256, 256, 0, stream>>>(xa, ln2w, ln2b, yt);
    // 10. hbuf = w_in @ y   (1020 x 16384) bf16
    mfma_gemm<0><<<dim3(16, 128), 256, 0, stream>>>(winB, yt, nullptr, hbuf,
                                                    1020, HW, 192);
    // 11. gbuf = gelu(dw(h)_lo) * dw(h)_hi   [c][p]
    dwg_kernel<<<dim3(8, 510), 256, 0, stream>>>(hbuf, wdw, gbuf);
    // 12. gt = gbuf^T  [p][512] (c pad zeroed)
    transpose_kernel<<<dim3(256, 8), 256, 0, stream>>>(gbuf, gt);
    // 13. out_b = xa + w_out @ g   (K=512 padded)
    mfma_gemm<1><<<dim3(3, 128), 256, 0, stream>>>(woutB, gt, xa, outb,
                                                   192, HW, 512);
  }
}

// Round 6
// 559.691 us; speedup vs baseline: 4.9558x; 1.2627x over previous
//
#include <hip/hip_runtime.h>
#include <hip/hip_bf16.h>
#include <math.h>

// ---------------------------------------------------------------------------
// Round 6: stage-wise batching (z-dim over the 4 batches) — 54 -> 14 launches.
//   - rownorm2 fused into dw_kernel (deterministic per-block partials)
//   - transpose fused into dwg_kernel (LDS tile, direct gt[p][512] output)
//   - FFN tail (dwg_t + w_out) split into 2 half-batches to bound gt size.
// d_ws is 256 MiB (observed via harness poison fills). Layout (bytes):
//   yt4    @ 0            25,165,824  bf16 [b][p][192]
//   qkva4  @ 25,165,824   75,497,472  bf16 [b][576][p]
//   qkvb4  @ 100,663,296  75,497,472  bf16 [b][576][p]
//   hbuf4  @ 25,165,824  134,217,728  bf16 [b][1024][p]  (aliases dead qkva/qkvb)
//   xa4    @ 176,160,768  50,331,648  fp32 [b][192][p]
//   gt2    @ 226,492,416  33,554,432  bf16 [z][p][512]   (half-batch)
//   wqkvB  @ 260,046,848     221,184
//   wprojB @ 260,268,032      73,728
//   winB   @ 260,341,760     393,216  (1024x192, rows >=1020 zero)
//   woutB  @ 260,734,976     196,608  (192x512, cols >=510 zero)
//   nrm2p  @ 260,931,584      49,152  fp32 [b][384][8]
//   Gpart  @ 260,980,736   2,359,296  fp32 [b][32][8][576]
//   P      @ 263,340,032      73,728  fp32 [b][8][576]
// total 263,413,760 <= 268,435,456. No atomics, no memsets.
// ---------------------------------------------------------------------------

#define HW_ 16384

typedef __attribute__((ext_vector_type(8))) short bf16x8;
typedef __attribute__((ext_vector_type(4))) float f32x4;
typedef __attribute__((ext_vector_type(16))) float f32x16;
typedef __attribute__((ext_vector_type(4))) int i32x4;

union Pack8 { __hip_bfloat16 h[8]; i32x4 v; };

// ---- weight fp32 -> bf16 conversion (with padding) -------------------------
__global__ __launch_bounds__(256) void convert_weights(
    const float* __restrict__ wqkv, const float* __restrict__ wproj,
    const float* __restrict__ win, const float* __restrict__ wout,
    __hip_bfloat16* __restrict__ oq, __hip_bfloat16* __restrict__ op,
    __hip_bfloat16* __restrict__ oi, __hip_bfloat16* __restrict__ oo) {
  const int i = blockIdx.x * 256 + threadIdx.x;
  if (i < 110592) oq[i] = __float2bfloat16(wqkv[i]);            // 576x192
  if (i < 36864)  op[i] = __float2bfloat16(wproj[i]);           // 192x192
  if (i < 196608) {                                             // 1024x192 pad
    int m = i / 192, k = i - m * 192;
    oi[i] = __float2bfloat16(m < 1020 ? win[m * 192 + k] : 0.f);
  }
  if (i < 98304) {                                              // 192x512 pad
    int m = i >> 9, k = i & 511;
    oo[i] = __float2bfloat16(k < 510 ? wout[m * 510 + k] : 0.f);
  }
}

// ---- channel LN -> transposed bf16 output [p][192]; grid (256, batch) ------
__global__ __launch_bounds__(256) void ln_t_kernel(
    const float* __restrict__ x, const float* __restrict__ w,
    const float* __restrict__ bi, __hip_bfloat16* __restrict__ yt) {
  const int b = blockIdx.y;
  x += (size_t)b * 192 * HW_;
  yt += (size_t)b * HW_ * 192;
  __shared__ float tile[192][68];
  __shared__ float psum[4][64], psq[4][64];
  __shared__ float mu_s[64], inv_s[64];
  const int tid = threadIdx.x;
  const int p0 = blockIdx.x * 64;
  for (int idx = tid; idx < 192 * 16; idx += 256) {
    int c = idx >> 4, p4 = idx & 15;
    f32x4 v = *(const f32x4*)(x + (size_t)c * HW_ + p0 + p4 * 4);
    *(f32x4*)&tile[c][p4 * 4] = v;
  }
  __syncthreads();
  const int tx = tid & 63, ty = tid >> 6;
  float s = 0.f, s2 = 0.f;
  for (int c = ty * 48; c < ty * 48 + 48; c++) {
    float v = tile[c][tx]; s += v; s2 += v * v;
  }
  psum[ty][tx] = s; psq[ty][tx] = s2;
  __syncthreads();
  if (ty == 0) {
    float ts = psum[0][tx] + psum[1][tx] + psum[2][tx] + psum[3][tx];
    float ts2 = psq[0][tx] + psq[1][tx] + psq[2][tx] + psq[3][tx];
    float mu = ts * (1.f / 192.f);
    float var = ts2 * (1.f / 192.f) - mu * mu;
    mu_s[tx] = mu; inv_s[tx] = rsqrtf(var + 1e-5f);
  }
  __syncthreads();
  for (int idx = tid; idx < 64 * 24; idx += 256) {
    int c8 = idx % 24, p = idx / 24;
    float mu = mu_s[p], inv = inv_s[p];
    Pack8 pk;
    #pragma unroll
    for (int u = 0; u < 8; u++) {
      int c = c8 * 8 + u;
      pk.h[u] = __float2bfloat16((tile[c][p] - mu) * inv * w[c] + bi[c]);
    }
    *(i32x4*)&yt[(size_t)(p0 + p) * 192 + c8 * 8] = pk.v;
  }
}

// ---- MFMA GEMM: D[M][N] = A[M][K] @ B_t[N][K]^T (+res); z = batch ----------
template <int EPI>
__global__ __launch_bounds__(256) void mfma_gemm(
    const __hip_bfloat16* __restrict__ A, const __hip_bfloat16* __restrict__ Bg,
    const float* __restrict__ Cres, void* __restrict__ Dout,
    int M, int N, int K, size_t Bstr, size_t Cstr, size_t Dstr) {
  const int z = blockIdx.z;
  const __hip_bfloat16* B = Bg + (size_t)z * Bstr;
  const float* C = Cres ? Cres + (size_t)z * Cstr : nullptr;
  __shared__ __align__(16) __hip_bfloat16 As[64][72];
  __shared__ __align__(16) __hip_bfloat16 Bs[128][72];
  const int tid = threadIdx.x;
  const int wave = tid >> 6, lane = tid & 63;
  const int quad = lane >> 4, lr = lane & 15;
  const int wm = (wave & 1) * 32, wn = (wave >> 1) * 64;
  const int row0 = blockIdx.x * 64, col0 = blockIdx.y * 128;

  f32x4 acc[2][4];
  #pragma unroll
  for (int i = 0; i < 2; i++)
    #pragma unroll
    for (int j = 0; j < 4; j++) acc[i][j] = (f32x4){0.f, 0.f, 0.f, 0.f};

  for (int k0 = 0; k0 < K; k0 += 64) {
    #pragma unroll
    for (int l = 0; l < 2; l++) {
      int t = tid + l * 256;
      int row = t >> 3, ch = t & 7;
      i32x4 v = *(const i32x4*)(A + (size_t)(row0 + row) * K + k0 + ch * 8);
      *(i32x4*)&As[row][ch * 8] = v;
    }
    #pragma unroll
    for (int l = 0; l < 4; l++) {
      int t = tid + l * 256;
      int row = t >> 3, ch = t & 7;
      i32x4 v = *(const i32x4*)(B + (size_t)(col0 + row) * K + k0 + ch * 8);
      *(i32x4*)&Bs[row][ch * 8] = v;
    }
    __syncthreads();
    #pragma unroll
    for (int ks = 0; ks < 2; ks++) {
      bf16x8 a0 = *(const bf16x8*)&As[wm + lr][ks * 32 + quad * 8];
      bf16x8 a1 = *(const bf16x8*)&As[wm + 16 + lr][ks * 32 + quad * 8];
      #pragma unroll
      for (int j = 0; j < 4; j++) {
        bf16x8 bb = *(const bf16x8*)&Bs[wn + j * 16 + lr][ks * 32 + quad * 8];
        acc[0][j] = __builtin_amdgcn_mfma_f32_16x16x32_bf16(a0, bb, acc[0][j], 0, 0, 0);
        acc[1][j] = __builtin_amdgcn_mfma_f32_16x16x32_bf16(a1, bb, acc[1][j], 0, 0, 0);
      }
    }
    __syncthreads();
  }

  #pragma unroll
  for (int i = 0; i < 2; i++) {
    #pragma unroll
    for (int r = 0; r < 4; r++) {
      int gm = row0 + wm + i * 16 + quad * 4 + r;
      if (gm >= M) continue;
      #pragma unroll
      for (int j = 0; j < 4; j++) {
        int gn = col0 + wn + j * 16 + lr;
        size_t idx = (size_t)gm * N + gn;
        if (EPI == 0) {
          (((__hip_bfloat16*)Dout) + (size_t)z * Dstr)[idx] = __float2bfloat16(acc[i][j][r]);
        } else {
          (((float*)Dout) + (size_t)z * Dstr)[idx] = acc[i][j][r] + C[idx];
        }
      }
    }
  }
}

// ---- depthwise 3x3 (8 px/thread) + fused q,k sum-of-squares partials -------
// grid (8 y-groups, 576 ch, 4 batch); nrm2p[b][c][yg] one store per block.
__global__ __launch_bounds__(256) void dw_kernel(
    const __hip_bfloat16* __restrict__ in, const float* __restrict__ wdw,
    __hip_bfloat16* __restrict__ out, float* __restrict__ nrm2p) {
  const int b = blockIdx.z;
  in  += (size_t)b * 576 * HW_;
  out += (size_t)b * 576 * HW_;
  const int c = blockIdx.y;
  const int x8 = threadIdx.x & 15;
  const int y = blockIdx.x * 16 + (threadIdx.x >> 4);
  const __hip_bfloat16* ip = in + (size_t)c * HW_;
  const float* wp = wdw + c * 9;
  float wv[9];
  #pragma unroll
  for (int u = 0; u < 9; u++) wv[u] = wp[u];
  float acc[8];
  #pragma unroll
  for (int j = 0; j < 8; j++) acc[j] = 0.f;
  #pragma unroll
  for (int r = 0; r < 3; r++) {
    int yy = y + r - 1;
    if (yy < 0 || yy >= 128) continue;
    const __hip_bfloat16* rp = ip + yy * 128 + x8 * 8;
    Pack8 mid; mid.v = *(const i32x4*)rp;
    float row[10];
    row[0] = (x8 > 0) ? (float)rp[-1] : 0.f;
    #pragma unroll
    for (int u = 0; u < 8; u++) row[1 + u] = (float)mid.h[u];
    row[9] = (x8 < 15) ? (float)rp[8] : 0.f;
    const float wl = wv[r * 3], wc = wv[r * 3 + 1], wr = wv[r * 3 + 2];
    #pragma unroll
    for (int j = 0; j < 8; j++)
      acc[j] += wl * row[j] + wc * row[j + 1] + wr * row[j + 2];
  }
  Pack8 o;
  #pragma unroll
  for (int j = 0; j < 8; j++) o.h[j] = __float2bfloat16(acc[j]);
  *(i32x4*)(out + (size_t)c * HW_ + y * 128 + x8 * 8) = o.v;
  if (c < 384) {
    float s = 0.f;
    #pragma unroll
    for (int j = 0; j < 8; j++) s += acc[j] * acc[j];
    #pragma unroll
    for (int off = 32; off > 0; off >>= 1) s += __shfl_down(s, off, 64);
    __shared__ float wsum[4];
    const int lane = threadIdx.x & 63, wvi = threadIdx.x >> 6;
    if (lane == 0) wsum[wvi] = s;
    __syncthreads();
    if (threadIdx.x == 0)
      nrm2p[((size_t)b * 384 + c) * 8 + blockIdx.x] =
          wsum[0] + wsum[1] + wsum[2] + wsum[3];
  }
}

// ---- MFMA Gram partials; grid (8 heads, 32 chunks, 4 batch) ----------------
__global__ __launch_bounds__(256) void gram_kernel(
    const __hip_bfloat16* __restrict__ qkv, float* __restrict__ Gpart) {
  const int b = blockIdx.z;
  qkv   += (size_t)b * 576 * HW_;
  Gpart += (size_t)b * 32 * 8 * 576;
  const int h = blockIdx.x, chunk = blockIdx.y;
  const int tid = threadIdx.x;
  const int w = tid >> 6, lane = tid & 63;
  const int m = lane & 31;
  const int khalf = lane >> 5;
  const __hip_bfloat16* qb = qkv + (size_t)(h * 24) * HW_;
  const __hip_bfloat16* kb = qkv + (size_t)(192 + h * 24) * HW_;
  f32x16 acc;
  #pragma unroll
  for (int i = 0; i < 16; i++) acc[i] = 0.f;
  const int e0 = chunk * 512 + w * 128;
  #pragma unroll
  for (int j = 0; j < 8; j++) {
    const int k0 = e0 + j * 16 + khalf * 8;
    bf16x8 a = *(const bf16x8*)(qb + (size_t)m * HW_ + k0);
    bf16x8 bfr = *(const bf16x8*)(kb + (size_t)m * HW_ + k0);
    acc = __builtin_amdgcn_mfma_f32_32x32x16_bf16(a, bfr, acc, 0, 0, 0);
  }
  __shared__ float gs[4][576];
  #pragma unroll
  for (int r = 0; r < 16; r++) {
    int row = (r & 3) + 8 * (r >> 2) + 4 * khalf;
    if (row < 24 && m < 24) gs[w][row * 24 + m] = acc[r];
  }
  __syncthreads();
  float* gp = Gpart + (size_t)(chunk * 8 + h) * 576;
  for (int t = tid; t < 576; t += 256)
    gp[t] = gs[0][t] + gs[1][t] + gs[2][t] + gs[3][t];
}

// ---- reduce Gpart + nrm2p partials, softmax -> P; grid (8 heads, 4 batch) --
__global__ __launch_bounds__(256) void softmax2_kernel(
    const float* __restrict__ Gpart, const float* __restrict__ nrm2p,
    const float* __restrict__ temp, float* __restrict__ P) {
  const int b = blockIdx.y;
  Gpart += (size_t)b * 32 * 8 * 576;
  nrm2p += (size_t)b * 384 * 8;
  P     += (size_t)b * 8 * 576;
  const int h = blockIdx.x;
  const int tid = threadIdx.x;
  __shared__ float Gs[576];
  __shared__ float nq[24], nk[24];
  for (int t = tid; t < 576; t += 256) {
    float s = 0.f;
    for (int ch = 0; ch < 32; ch++)
      s += Gpart[(size_t)(ch * 8 + h) * 576 + t];
    Gs[t] = s;
  }
  if (tid < 48) {
    const int r = (tid < 24) ? (h * 24 + tid) : (192 + h * 24 + tid - 24);
    float s = 0.f;
    #pragma unroll
    for (int j = 0; j < 8; j++) s += nrm2p[(size_t)r * 8 + j];
    float nv = fmaxf(sqrtf(s), 1e-12f);
    if (tid < 24) nq[tid] = nv; else nk[tid - 24] = nv;
  }
  __syncthreads();
  if (tid < 24) {
    const int d = tid;
    const float tp = temp[h];
    float row[24], mx = -1e30f;
    #pragma unroll
    for (int c = 0; c < 24; c++) {
      float v = Gs[d * 24 + c] * tp / (nq[d] * nk[c]);
      row[c] = v; mx = fmaxf(mx, v);
    }
    float s = 0.f;
    #pragma unroll
    for (int c = 0; c < 24; c++) { float e = expf(row[c] - mx); row[c] = e; s += e; }
    const float inv = 1.f / s;
    #pragma unroll
    for (int c = 0; c < 24; c++) P[h * 576 + d * 24 + c] = row[c] * inv;
  }
}

// ---- out_t[e][h*24+d] = sum_c P[h,d,c]*v[h,c,e]; grid (8, 64, 4) -----------
__global__ __launch_bounds__(256) void pv_kernel(
    const float* __restrict__ P, const __hip_bfloat16* __restrict__ qkv,
    __hip_bfloat16* __restrict__ yt) {
  const int b = blockIdx.z;
  P   += (size_t)b * 8 * 576;
  qkv += (size_t)b * 576 * HW_;
  yt  += (size_t)b * HW_ * 192;
  const int hh = blockIdx.x;
  const int e = blockIdx.y * 256 + threadIdx.x;
  __shared__ float Ps[576];
  for (int t = threadIdx.x; t < 576; t += 256) Ps[t] = P[hh * 576 + t];
  __syncthreads();
  const __hip_bfloat16* vb = qkv + (size_t)(384 + hh * 24) * HW_;
  float acc[24];
  #pragma unroll
  for (int d = 0; d < 24; d++) acc[d] = 0.f;
  for (int c = 0; c < 24; c++) {
    float v = (float)vb[(size_t)c * HW_ + e];
    #pragma unroll
    for (int d = 0; d < 24; d++) acc[d] += Ps[d * 24 + c] * v;
  }
  #pragma unroll
  for (int g = 0; g < 3; g++) {
    Pack8 pk;
    #pragma unroll
    for (int u = 0; u < 8; u++) pk.h[u] = __float2bfloat16(acc[g * 8 + u]);
    *(i32x4*)&yt[(size_t)e * 192 + hh * 24 + g * 8] = pk.v;
  }
}

// ---- FFN depthwise + GELU gate -> transposed gt[p][512] via LDS tile -------
// grid (256 = y*2+xh, 16 ch-groups, 2 half-batch); b = b0 + z.
__global__ __launch_bounds__(256) void dwg_t_kernel(
    const __hip_bfloat16* __restrict__ hsrc, const float* __restrict__ wdw,
    __hip_bfloat16* __restrict__ gt, int b0) {
  const int z = blockIdx.z;
  const int bb = b0 + z;
  const int y = blockIdx.x >> 1, xh = blockIdx.x & 1;
  const int cz = blockIdx.y;
  const int tid = threadIdx.x;
  const int cl = tid >> 3, pg = tid & 7;          // 32 ch x 8 px-groups
  const int c = cz * 32 + cl;
  const int px = xh * 64 + pg * 8;
  __shared__ __hip_bfloat16 sg[32][72];
  Pack8 o;
  if (c < 510) {
    const __hip_bfloat16* ha = hsrc + ((size_t)bb * 1024 + c) * HW_;
    const __hip_bfloat16* hb = hsrc + ((size_t)bb * 1024 + c + 510) * HW_;
    const float* wa = wdw + c * 9;
    const float* wb = wdw + (c + 510) * 9;
    float wva[9], wvb[9];
    #pragma unroll
    for (int u = 0; u < 9; u++) { wva[u] = wa[u]; wvb[u] = wb[u]; }
    float s1[8], s2[8];
    #pragma unroll
    for (int j = 0; j < 8; j++) { s1[j] = 0.f; s2[j] = 0.f; }
    #pragma unroll
    for (int r = 0; r < 3; r++) {
      int yy = y + r - 1;
      if (yy < 0 || yy >= 128) continue;
      const int off = yy * 128 + px;
      Pack8 ma; ma.v = *(const i32x4*)(ha + off);
      Pack8 mb; mb.v = *(const i32x4*)(hb + off);
      float rowa[10], rowb[10];
      rowa[0] = (px > 0) ? (float)ha[off - 1] : 0.f;
      rowb[0] = (px > 0) ? (float)hb[off - 1] : 0.f;
      #pragma unroll
      for (int u = 0; u < 8; u++) { rowa[1 + u] = (float)ma.h[u]; rowb[1 + u] = (float)mb.h[u]; }
      rowa[9] = (px < 120) ? (float)ha[off + 8] : 0.f;
      rowb[9] = (px < 120) ? (float)hb[off + 8] : 0.f;
      const float al = wva[r * 3], ac = wva[r * 3 + 1], ar = wva[r * 3 + 2];
      const float bl = wvb[r * 3], bc = wvb[r * 3 + 1], br = wvb[r * 3 + 2];
      #pragma unroll
      for (int j = 0; j < 8; j++) {
        s1[j] += al * rowa[j] + ac * rowa[j + 1] + ar * rowa[j + 2];
        s2[j] += bl * rowb[j] + bc * rowb[j + 1] + br * rowb[j + 2];
      }
    }
    #pragma unroll
    for (int j = 0; j < 8; j++) {
      float ge = 0.5f * s1[j] * (1.f + erff(s1[j] * 0.70710678118654752f));
      o.h[j] = __float2bfloat16(ge * s2[j]);
    }
  } else {
    #pragma unroll
    for (int j = 0; j < 8; j++) o.h[j] = __float2bfloat16(0.f);
  }
  #pragma unroll
  for (int j = 0; j < 8; j++) sg[cl][pg * 8 + j] = o.h[j];
  __syncthreads();
  // transposed write: 64 pixel-rows x 32 ch (64B each), 4 threads/row
  const int prow = tid >> 2, coff = (tid & 3) * 8;
  Pack8 w8;
  #pragma unroll
  for (int u = 0; u < 8; u++) w8.h[u] = sg[coff + u][prow];
  *(i32x4*)(gt + ((size_t)z * HW_ + y * 128 + xh * 64 + prow) * 512 + cz * 32 + coff) = w8.v;
}

// ---------------------------------------------------------------------------
extern "C" void kernel_launch(void* const* d_in, const int* in_sizes, int n_in,
                              void* d_out, int out_size, void* d_ws, size_t ws_size,
                              hipStream_t stream) {
  const float* x     = (const float*)d_in[0];
  const float* temp  = (const float*)d_in[1];
  const float* ln1w  = (const float*)d_in[2];
  const float* ln1b  = (const float*)d_in[3];
  const float* ln2w  = (const float*)d_in[4];
  const float* ln2b  = (const float*)d_in[5];
  const float* wqkv  = (const float*)d_in[6];
  const float* wqkvdw= (const float*)d_in[7];
  const float* wproj = (const float*)d_in[8];
  const float* win   = (const float*)d_in[9];
  const float* wdw   = (const float*)d_in[10];
  const float* wout  = (const float*)d_in[11];
  float* out = (float*)d_out;
  char* ws = (char*)d_ws;

  const int HW = 16384;
  const size_t HWC = (size_t)192 * HW;

  __hip_bfloat16* yt    = (__hip_bfloat16*)(ws + 0);
  __hip_bfloat16* qkva  = (__hip_bfloat16*)(ws + 25165824);
  __hip_bfloat16* qkvb  = (__hip_bfloat16*)(ws + 100663296);
  __hip_bfloat16* hbuf  = (__hip_bfloat16*)(ws + 25165824);   // aliases dead qkva/qkvb
  float*          xa    = (float*)(ws + 176160768);
  __hip_bfloat16* gt    = (__hip_bfloat16*)(ws + 226492416);  // 2 half-batches
  __hip_bfloat16* wqkvB = (__hip_bfloat16*)(ws + 260046848);
  __hip_bfloat16* wprojB= (__hip_bfloat16*)(ws + 260268032);
  __hip_bfloat16* winB  = (__hip_bfloat16*)(ws + 260341760);
  __hip_bfloat16* woutB = (__hip_bfloat16*)(ws + 260734976);
  float*          nrm2p = (float*)(ws + 260931584);
  float*          Gpart = (float*)(ws + 260980736);
  float*          P     = (float*)(ws + 263340032);

  convert_weights<<<768, 256, 0, stream>>>(wqkv, wproj, win, wout,
                                           wqkvB, wprojB, winB, woutB);

  // 1. yt = LN1(x), all batches
  ln_t_kernel<<<dim3(256, 4), 256, 0, stream>>>(x, ln1w, ln1b, yt);
  // 2. qkva = w_qkv @ y   (576 x 16384) x4
  mfma_gemm<0><<<dim3(9, 128, 4), 256, 0, stream>>>(
      wqkvB, yt, nullptr, qkva, 576, HW, 192,
      (size_t)HW * 192, 0, (size_t)576 * HW);
  // 3. qkvb = dwconv3x3(qkva) + nrm2 partials
  dw_kernel<<<dim3(8, 576, 4), 256, 0, stream>>>(qkva, wqkvdw, qkvb, nrm2p);
  // 4. Gram partials via MFMA
  gram_kernel<<<dim3(8, 32, 4), 256, 0, stream>>>(qkvb, Gpart);
  // 5. P = softmax(reduce(Gpart) * temp / (|q||k|))
  softmax2_kernel<<<dim3(8, 4), 256, 0, stream>>>(Gpart, nrm2p, temp, P);
  // 6. yt = (P @ v)^T bf16
  pv_kernel<<<dim3(8, 64, 4), 256, 0, stream>>>(P, qkvb, yt);
  // 7. xa = x + w_proj @ pv
  mfma_gemm<1><<<dim3(3, 128, 4), 256, 0, stream>>>(
      wprojB, yt, x, xa, 192, HW, 192,
      (size_t)HW * 192, HWC, HWC);
  // 8. yt = LN2(xa)
  ln_t_kernel<<<dim3(256, 4), 256, 0, stream>>>(xa, ln2w, ln2b, yt);
  // 9. hbuf = w_in @ y   (1020 x 16384) x4  (overwrites dead qkva/qkvb)
  mfma_gemm<0><<<dim3(16, 128, 4), 256, 0, stream>>>(
      winB, yt, nullptr, hbuf, 1020, HW, 192,
      (size_t)HW * 192, 0, (size_t)1024 * HW);
  // 10-13. FFN tail in two half-batches: gate(+transpose) then w_out GEMM
  for (int half = 0; half < 2; half++) {
    const int b0 = half * 2;
    dwg_t_kernel<<<dim3(256, 16, 2), 256, 0, stream>>>(hbuf, wdw, gt, b0);
    mfma_gemm<1><<<dim3(3, 128, 2), 256, 0, stream>>>(
        woutB, gt, xa + (size_t)b0 * HWC, out + (size_t)b0 * HWC,
        192, HW, 512, (size_t)HW * 512, HWC, HWC);
  }
}

// Round 7
// 509.347 us; speedup vs baseline: 5.4457x; 1.0988x over previous
//
#include <hip/hip_runtime.h>
#include <hip/hip_bf16.h>
#include <math.h>

// ---------------------------------------------------------------------------
// Round 7: dwg_t re-tiled to 8 rows/block (rolling-window, single fetch of
// each hbuf row per block) — kills the 3x vertical fetch amplification seen
// in round 6 (FETCH 195 MB vs 67 MB ideal). LDS pad 522 for ~conflict-free
// transpose. Everything else identical to round 6.
//
// ws layout (bytes):
//   yt4    @ 0            25,165,824  bf16 [b][p][192]
//   qkva4  @ 25,165,824   75,497,472  bf16 [b][576][p]
//   qkvb4  @ 100,663,296  75,497,472  bf16 [b][576][p]
//   hbuf4  @ 25,165,824  134,217,728  bf16 [b][1024][p]  (aliases dead qkva/qkvb)
//   xa4    @ 176,160,768  50,331,648  fp32 [b][192][p]
//   gt2    @ 226,492,416  33,554,432  bf16 [z][p][512]   (half-batch)
//   wqkvB  @ 260,046,848     221,184
//   wprojB @ 260,268,032      73,728
//   winB   @ 260,341,760     393,216  (1024x192, rows >=1020 zero)
//   woutB  @ 260,734,976     196,608  (192x512, cols >=510 zero)
//   nrm2p  @ 260,931,584      49,152  fp32 [b][384][8]
//   Gpart  @ 260,980,736   2,359,296  fp32 [b][32][8][576]
//   P      @ 263,340,032      73,728  fp32 [b][8][576]
// total 263,413,760 <= 268,435,456. No atomics, no memsets.
// ---------------------------------------------------------------------------

#define HW_ 16384

typedef __attribute__((ext_vector_type(8))) short bf16x8;
typedef __attribute__((ext_vector_type(4))) float f32x4;
typedef __attribute__((ext_vector_type(16))) float f32x16;
typedef __attribute__((ext_vector_type(4))) int i32x4;

union Pack8 { __hip_bfloat16 h[8]; i32x4 v; };

// ---- weight fp32 -> bf16 conversion (with padding) -------------------------
__global__ __launch_bounds__(256) void convert_weights(
    const float* __restrict__ wqkv, const float* __restrict__ wproj,
    const float* __restrict__ win, const float* __restrict__ wout,
    __hip_bfloat16* __restrict__ oq, __hip_bfloat16* __restrict__ op,
    __hip_bfloat16* __restrict__ oi, __hip_bfloat16* __restrict__ oo) {
  const int i = blockIdx.x * 256 + threadIdx.x;
  if (i < 110592) oq[i] = __float2bfloat16(wqkv[i]);            // 576x192
  if (i < 36864)  op[i] = __float2bfloat16(wproj[i]);           // 192x192
  if (i < 196608) {                                             // 1024x192 pad
    int m = i / 192, k = i - m * 192;
    oi[i] = __float2bfloat16(m < 1020 ? win[m * 192 + k] : 0.f);
  }
  if (i < 98304) {                                              // 192x512 pad
    int m = i >> 9, k = i & 511;
    oo[i] = __float2bfloat16(k < 510 ? wout[m * 510 + k] : 0.f);
  }
}

// ---- channel LN -> transposed bf16 output [p][192]; grid (256, batch) ------
__global__ __launch_bounds__(256) void ln_t_kernel(
    const float* __restrict__ x, const float* __restrict__ w,
    const float* __restrict__ bi, __hip_bfloat16* __restrict__ yt) {
  const int b = blockIdx.y;
  x += (size_t)b * 192 * HW_;
  yt += (size_t)b * HW_ * 192;
  __shared__ float tile[192][68];
  __shared__ float psum[4][64], psq[4][64];
  __shared__ float mu_s[64], inv_s[64];
  const int tid = threadIdx.x;
  const int p0 = blockIdx.x * 64;
  for (int idx = tid; idx < 192 * 16; idx += 256) {
    int c = idx >> 4, p4 = idx & 15;
    f32x4 v = *(const f32x4*)(x + (size_t)c * HW_ + p0 + p4 * 4);
    *(f32x4*)&tile[c][p4 * 4] = v;
  }
  __syncthreads();
  const int tx = tid & 63, ty = tid >> 6;
  float s = 0.f, s2 = 0.f;
  for (int c = ty * 48; c < ty * 48 + 48; c++) {
    float v = tile[c][tx]; s += v; s2 += v * v;
  }
  psum[ty][tx] = s; psq[ty][tx] = s2;
  __syncthreads();
  if (ty == 0) {
    float ts = psum[0][tx] + psum[1][tx] + psum[2][tx] + psum[3][tx];
    float ts2 = psq[0][tx] + psq[1][tx] + psq[2][tx] + psq[3][tx];
    float mu = ts * (1.f / 192.f);
    float var = ts2 * (1.f / 192.f) - mu * mu;
    mu_s[tx] = mu; inv_s[tx] = rsqrtf(var + 1e-5f);
  }
  __syncthreads();
  for (int idx = tid; idx < 64 * 24; idx += 256) {
    int c8 = idx % 24, p = idx / 24;
    float mu = mu_s[p], inv = inv_s[p];
    Pack8 pk;
    #pragma unroll
    for (int u = 0; u < 8; u++) {
      int c = c8 * 8 + u;
      pk.h[u] = __float2bfloat16((tile[c][p] - mu) * inv * w[c] + bi[c]);
    }
    *(i32x4*)&yt[(size_t)(p0 + p) * 192 + c8 * 8] = pk.v;
  }
}

// ---- MFMA GEMM: D[M][N] = A[M][K] @ B_t[N][K]^T (+res); z = batch ----------
template <int EPI>
__global__ __launch_bounds__(256) void mfma_gemm(
    const __hip_bfloat16* __restrict__ A, const __hip_bfloat16* __restrict__ Bg,
    const float* __restrict__ Cres, void* __restrict__ Dout,
    int M, int N, int K, size_t Bstr, size_t Cstr, size_t Dstr) {
  const int z = blockIdx.z;
  const __hip_bfloat16* B = Bg + (size_t)z * Bstr;
  const float* C = Cres ? Cres + (size_t)z * Cstr : nullptr;
  __shared__ __align__(16) __hip_bfloat16 As[64][72];
  __shared__ __align__(16) __hip_bfloat16 Bs[128][72];
  const int tid = threadIdx.x;
  const int wave = tid >> 6, lane = tid & 63;
  const int quad = lane >> 4, lr = lane & 15;
  const int wm = (wave & 1) * 32, wn = (wave >> 1) * 64;
  const int row0 = blockIdx.x * 64, col0 = blockIdx.y * 128;

  f32x4 acc[2][4];
  #pragma unroll
  for (int i = 0; i < 2; i++)
    #pragma unroll
    for (int j = 0; j < 4; j++) acc[i][j] = (f32x4){0.f, 0.f, 0.f, 0.f};

  for (int k0 = 0; k0 < K; k0 += 64) {
    #pragma unroll
    for (int l = 0; l < 2; l++) {
      int t = tid + l * 256;
      int row = t >> 3, ch = t & 7;
      i32x4 v = *(const i32x4*)(A + (size_t)(row0 + row) * K + k0 + ch * 8);
      *(i32x4*)&As[row][ch * 8] = v;
    }
    #pragma unroll
    for (int l = 0; l < 4; l++) {
      int t = tid + l * 256;
      int row = t >> 3, ch = t & 7;
      i32x4 v = *(const i32x4*)(B + (size_t)(col0 + row) * K + k0 + ch * 8);
      *(i32x4*)&Bs[row][ch * 8] = v;
    }
    __syncthreads();
    #pragma unroll
    for (int ks = 0; ks < 2; ks++) {
      bf16x8 a0 = *(const bf16x8*)&As[wm + lr][ks * 32 + quad * 8];
      bf16x8 a1 = *(const bf16x8*)&As[wm + 16 + lr][ks * 32 + quad * 8];
      #pragma unroll
      for (int j = 0; j < 4; j++) {
        bf16x8 bb = *(const bf16x8*)&Bs[wn + j * 16 + lr][ks * 32 + quad * 8];
        acc[0][j] = __builtin_amdgcn_mfma_f32_16x16x32_bf16(a0, bb, acc[0][j], 0, 0, 0);
        acc[1][j] = __builtin_amdgcn_mfma_f32_16x16x32_bf16(a1, bb, acc[1][j], 0, 0, 0);
      }
    }
    __syncthreads();
  }

  #pragma unroll
  for (int i = 0; i < 2; i++) {
    #pragma unroll
    for (int r = 0; r < 4; r++) {
      int gm = row0 + wm + i * 16 + quad * 4 + r;
      if (gm >= M) continue;
      #pragma unroll
      for (int j = 0; j < 4; j++) {
        int gn = col0 + wn + j * 16 + lr;
        size_t idx = (size_t)gm * N + gn;
        if (EPI == 0) {
          (((__hip_bfloat16*)Dout) + (size_t)z * Dstr)[idx] = __float2bfloat16(acc[i][j][r]);
        } else {
          (((float*)Dout) + (size_t)z * Dstr)[idx] = acc[i][j][r] + C[idx];
        }
      }
    }
  }
}

// ---- depthwise 3x3 (8 px/thread) + fused q,k sum-of-squares partials -------
__global__ __launch_bounds__(256) void dw_kernel(
    const __hip_bfloat16* __restrict__ in, const float* __restrict__ wdw,
    __hip_bfloat16* __restrict__ out, float* __restrict__ nrm2p) {
  const int b = blockIdx.z;
  in  += (size_t)b * 576 * HW_;
  out += (size_t)b * 576 * HW_;
  const int c = blockIdx.y;
  const int x8 = threadIdx.x & 15;
  const int y = blockIdx.x * 16 + (threadIdx.x >> 4);
  const __hip_bfloat16* ip = in + (size_t)c * HW_;
  const float* wp = wdw + c * 9;
  float wv[9];
  #pragma unroll
  for (int u = 0; u < 9; u++) wv[u] = wp[u];
  float acc[8];
  #pragma unroll
  for (int j = 0; j < 8; j++) acc[j] = 0.f;
  #pragma unroll
  for (int r = 0; r < 3; r++) {
    int yy = y + r - 1;
    if (yy < 0 || yy >= 128) continue;
    const __hip_bfloat16* rp = ip + yy * 128 + x8 * 8;
    Pack8 mid; mid.v = *(const i32x4*)rp;
    float row[10];
    row[0] = (x8 > 0) ? (float)rp[-1] : 0.f;
    #pragma unroll
    for (int u = 0; u < 8; u++) row[1 + u] = (float)mid.h[u];
    row[9] = (x8 < 15) ? (float)rp[8] : 0.f;
    const float wl = wv[r * 3], wc = wv[r * 3 + 1], wr = wv[r * 3 + 2];
    #pragma unroll
    for (int j = 0; j < 8; j++)
      acc[j] += wl * row[j] + wc * row[j + 1] + wr * row[j + 2];
  }
  Pack8 o;
  #pragma unroll
  for (int j = 0; j < 8; j++) o.h[j] = __float2bfloat16(acc[j]);
  *(i32x4*)(out + (size_t)c * HW_ + y * 128 + x8 * 8) = o.v;
  if (c < 384) {
    float s = 0.f;
    #pragma unroll
    for (int j = 0; j < 8; j++) s += acc[j] * acc[j];
    #pragma unroll
    for (int off = 32; off > 0; off >>= 1) s += __shfl_down(s, off, 64);
    __shared__ float wsum[4];
    const int lane = threadIdx.x & 63, wvi = threadIdx.x >> 6;
    if (lane == 0) wsum[wvi] = s;
    __syncthreads();
    if (threadIdx.x == 0)
      nrm2p[((size_t)b * 384 + c) * 8 + blockIdx.x] =
          wsum[0] + wsum[1] + wsum[2] + wsum[3];
  }
}

// ---- MFMA Gram partials; grid (8 heads, 32 chunks, 4 batch) ----------------
__global__ __launch_bounds__(256) void gram_kernel(
    const __hip_bfloat16* __restrict__ qkv, float* __restrict__ Gpart) {
  const int b = blockIdx.z;
  qkv   += (size_t)b * 576 * HW_;
  Gpart += (size_t)b * 32 * 8 * 576;
  const int h = blockIdx.x, chunk = blockIdx.y;
  const int tid = threadIdx.x;
  const int w = tid >> 6, lane = tid & 63;
  const int m = lane & 31;
  const int khalf = lane >> 5;
  const __hip_bfloat16* qb = qkv + (size_t)(h * 24) * HW_;
  const __hip_bfloat16* kb = qkv + (size_t)(192 + h * 24) * HW_;
  f32x16 acc;
  #pragma unroll
  for (int i = 0; i < 16; i++) acc[i] = 0.f;
  const int e0 = chunk * 512 + w * 128;
  #pragma unroll
  for (int j = 0; j < 8; j++) {
    const int k0 = e0 + j * 16 + khalf * 8;
    bf16x8 a = *(const bf16x8*)(qb + (size_t)m * HW_ + k0);
    bf16x8 bfr = *(const bf16x8*)(kb + (size_t)m * HW_ + k0);
    acc = __builtin_amdgcn_mfma_f32_32x32x16_bf16(a, bfr, acc, 0, 0, 0);
  }
  __shared__ float gs[4][576];
  #pragma unroll
  for (int r = 0; r < 16; r++) {
    int row = (r & 3) + 8 * (r >> 2) + 4 * khalf;
    if (row < 24 && m < 24) gs[w][row * 24 + m] = acc[r];
  }
  __syncthreads();
  float* gp = Gpart + (size_t)(chunk * 8 + h) * 576;
  for (int t = tid; t < 576; t += 256)
    gp[t] = gs[0][t] + gs[1][t] + gs[2][t] + gs[3][t];
}

// ---- reduce Gpart + nrm2p partials, softmax -> P; grid (8 heads, 4 batch) --
__global__ __launch_bounds__(256) void softmax2_kernel(
    const float* __restrict__ Gpart, const float* __restrict__ nrm2p,
    const float* __restrict__ temp, float* __restrict__ P) {
  const int b = blockIdx.y;
  Gpart += (size_t)b * 32 * 8 * 576;
  nrm2p += (size_t)b * 384 * 8;
  P     += (size_t)b * 8 * 576;
  const int h = blockIdx.x;
  const int tid = threadIdx.x;
  __shared__ float Gs[576];
  __shared__ float nq[24], nk[24];
  for (int t = tid; t < 576; t += 256) {
    float s = 0.f;
    for (int ch = 0; ch < 32; ch++)
      s += Gpart[(size_t)(ch * 8 + h) * 576 + t];
    Gs[t] = s;
  }
  if (tid < 48) {
    const int r = (tid < 24) ? (h * 24 + tid) : (192 + h * 24 + tid - 24);
    float s = 0.f;
    #pragma unroll
    for (int j = 0; j < 8; j++) s += nrm2p[(size_t)r * 8 + j];
    float nv = fmaxf(sqrtf(s), 1e-12f);
    if (tid < 24) nq[tid] = nv; else nk[tid - 24] = nv;
  }
  __syncthreads();
  if (tid < 24) {
    const int d = tid;
    const float tp = temp[h];
    float row[24], mx = -1e30f;
    #pragma unroll
    for (int c = 0; c < 24; c++) {
      float v = Gs[d * 24 + c] * tp / (nq[d] * nk[c]);
      row[c] = v; mx = fmaxf(mx, v);
    }
    float s = 0.f;
    #pragma unroll
    for (int c = 0; c < 24; c++) { float e = expf(row[c] - mx); row[c] = e; s += e; }
    const float inv = 1.f / s;
    #pragma unroll
    for (int c = 0; c < 24; c++) P[h * 576 + d * 24 + c] = row[c] * inv;
  }
}

// ---- out_t[e][h*24+d] = sum_c P[h,d,c]*v[h,c,e]; grid (8, 64, 4) -----------
__global__ __launch_bounds__(256) void pv_kernel(
    const float* __restrict__ P, const __hip_bfloat16* __restrict__ qkv,
    __hip_bfloat16* __restrict__ yt) {
  const int b = blockIdx.z;
  P   += (size_t)b * 8 * 576;
  qkv += (size_t)b * 576 * HW_;
  yt  += (size_t)b * HW_ * 192;
  const int hh = blockIdx.x;
  const int e = blockIdx.y * 256 + threadIdx.x;
  __shared__ float Ps[576];
  for (int t = threadIdx.x; t < 576; t += 256) Ps[t] = P[hh * 576 + t];
  __syncthreads();
  const __hip_bfloat16* vb = qkv + (size_t)(384 + hh * 24) * HW_;
  float acc[24];
  #pragma unroll
  for (int d = 0; d < 24; d++) acc[d] = 0.f;
  for (int c = 0; c < 24; c++) {
    float v = (float)vb[(size_t)c * HW_ + e];
    #pragma unroll
    for (int d = 0; d < 24; d++) acc[d] += Ps[d * 24 + c] * v;
  }
  #pragma unroll
  for (int g = 0; g < 3; g++) {
    Pack8 pk;
    #pragma unroll
    for (int u = 0; u < 8; u++) pk.h[u] = __float2bfloat16(acc[g * 8 + u]);
    *(i32x4*)&yt[(size_t)e * 192 + hh * 24 + g * 8] = pk.v;
  }
}

// ---- FFN depthwise + GELU gate -> transposed gt[p][512], 8-row tiles -------
// grid (32 = yt*2+xh, 16 ch-groups, 2 batch-within-half). Block: 32 ch x
// 8 rows x 64 px. Rolling pass over 10 input rows: each hbuf row fetched
// once per block (vertical overfetch 1.25x vs round-6's 3x).
__global__ __launch_bounds__(256) void dwg_t_kernel(
    const __hip_bfloat16* __restrict__ hsrc, const float* __restrict__ wdw,
    __hip_bfloat16* __restrict__ gt, int b0) {
  const int z = blockIdx.z;
  const int bb = b0 + z;
  const int yt = blockIdx.x >> 1, xh = blockIdx.x & 1;
  const int cz = blockIdx.y;
  const int tid = threadIdx.x;
  const int cl = tid >> 3, x8 = tid & 7;         // 32 ch x 8 px-groups
  const int c = cz * 32 + cl;
  const int y0 = yt * 8;
  const int pxb = xh * 64 + x8 * 8;              // global px base
  __shared__ __hip_bfloat16 sg[32][522];         // [ch][8*64] pad->522

  const bool active = (c < 510);
  const int ca = active ? c : 0;
  const __hip_bfloat16* ha = hsrc + ((size_t)bb * 1024 + ca) * HW_;
  const __hip_bfloat16* hb = hsrc + ((size_t)bb * 1024 + ca + 510) * HW_;
  float wva[9], wvb[9];
  #pragma unroll
  for (int u = 0; u < 9; u++) {
    wva[u] = active ? wdw[c * 9 + u] : 0.f;
    wvb[u] = active ? wdw[(c + 510) * 9 + u] : 0.f;
  }

  float aA[3][8], aB[3][8];
  #pragma unroll
  for (int s = 0; s < 3; s++)
    #pragma unroll
    for (int j = 0; j < 8; j++) { aA[s][j] = 0.f; aB[s][j] = 0.f; }

  #pragma unroll
  for (int i = 0; i < 10; i++) {
    const int ry = y0 - 1 + i;
    float ra[10], rb[10];
    if (ry >= 0 && ry < 128) {
      const int off = ry * 128 + pxb;
      Pack8 ma; ma.v = *(const i32x4*)(ha + off);
      Pack8 mb; mb.v = *(const i32x4*)(hb + off);
      ra[0] = (pxb > 0) ? (float)ha[off - 1] : 0.f;
      rb[0] = (pxb > 0) ? (float)hb[off - 1] : 0.f;
      #pragma unroll
      for (int u = 0; u < 8; u++) { ra[1 + u] = (float)ma.h[u]; rb[1 + u] = (float)mb.h[u]; }
      ra[9] = (pxb < 120) ? (float)ha[off + 8] : 0.f;
      rb[9] = (pxb < 120) ? (float)hb[off + 8] : 0.f;
    } else {
      #pragma unroll
      for (int u = 0; u < 10; u++) { ra[u] = 0.f; rb[u] = 0.f; }
    }
    // input row ry feeds output rows lo = i-r (weight-row r)
    #pragma unroll
    for (int r = 0; r < 3; r++) {
      const int lo = i - r;
      if (lo < 0 || lo >= 8) continue;
      const int s = lo % 3;
      const float a0 = wva[r * 3], a1 = wva[r * 3 + 1], a2 = wva[r * 3 + 2];
      const float b0w = wvb[r * 3], b1 = wvb[r * 3 + 1], b2 = wvb[r * 3 + 2];
      #pragma unroll
      for (int j = 0; j < 8; j++) {
        aA[s][j] += a0 * ra[j] + a1 * ra[j + 1] + a2 * ra[j + 2];
        aB[s][j] += b0w * rb[j] + b1 * rb[j + 1] + b2 * rb[j + 2];
      }
    }
    // output row lo = i-2 is complete: gate + stage to LDS, recycle slot
    {
      const int lo = i - 2;
      if (lo >= 0 && lo < 8) {
        const int s = lo % 3;
        Pack8 o;
        #pragma unroll
        for (int j = 0; j < 8; j++) {
          float v = aA[s][j];
          float ge = 0.5f * v * (1.f + erff(v * 0.70710678118654752f));
          o.h[j] = __float2bfloat16(ge * aB[s][j]);
          aA[s][j] = 0.f; aB[s][j] = 0.f;
        }
        *(i32x4*)&sg[cl][lo * 64 + x8 * 8] = o.v;
      }
    }
  }
  __syncthreads();
  // transposed write: 512 local px x 32 ch; 4 lanes cover one 64B px segment
  const int sp = tid >> 2, ch0 = (tid & 3) * 8;
  #pragma unroll
  for (int k = 0; k < 8; k++) {
    Pack8 o;
    #pragma unroll
    for (int u = 0; u < 8; u++) o.h[u] = sg[ch0 + u][k * 64 + sp];
    const int gp = (y0 + k) * 128 + xh * 64 + sp;
    *(i32x4*)&gt[((size_t)z * HW_ + gp) * 512 + cz * 32 + ch0] = o.v;
  }
}

// ---------------------------------------------------------------------------
extern "C" void kernel_launch(void* const* d_in, const int* in_sizes, int n_in,
                              void* d_out, int out_size, void* d_ws, size_t ws_size,
                              hipStream_t stream) {
  const float* x     = (const float*)d_in[0];
  const float* temp  = (const float*)d_in[1];
  const float* ln1w  = (const float*)d_in[2];
  const float* ln1b  = (const float*)d_in[3];
  const float* ln2w  = (const float*)d_in[4];
  const float* ln2b  = (const float*)d_in[5];
  const float* wqkv  = (const float*)d_in[6];
  const float* wqkvdw= (const float*)d_in[7];
  const float* wproj = (const float*)d_in[8];
  const float* win   = (const float*)d_in[9];
  const float* wdw   = (const float*)d_in[10];
  const float* wout  = (const float*)d_in[11];
  float* out = (float*)d_out;
  char* ws = (char*)d_ws;

  const int HW = 16384;
  const size_t HWC = (size_t)192 * HW;

  __hip_bfloat16* yt    = (__hip_bfloat16*)(ws + 0);
  __hip_bfloat16* qkva  = (__hip_bfloat16*)(ws + 25165824);
  __hip_bfloat16* qkvb  = (__hip_bfloat16*)(ws + 100663296);
  __hip_bfloat16* hbuf  = (__hip_bfloat16*)(ws + 25165824);   // aliases dead qkva/qkvb
  float*          xa    = (float*)(ws + 176160768);
  __hip_bfloat16* gt    = (__hip_bfloat16*)(ws + 226492416);  // 2 half-batches
  __hip_bfloat16* wqkvB = (__hip_bfloat16*)(ws + 260046848);
  __hip_bfloat16* wprojB= (__hip_bfloat16*)(ws + 260268032);
  __hip_bfloat16* winB  = (__hip_bfloat16*)(ws + 260341760);
  __hip_bfloat16* woutB = (__hip_bfloat16*)(ws + 260734976);
  float*          nrm2p = (float*)(ws + 260931584);
  float*          Gpart = (float*)(ws + 260980736);
  float*          P     = (float*)(ws + 263340032);

  convert_weights<<<768, 256, 0, stream>>>(wqkv, wproj, win, wout,
                                           wqkvB, wprojB, winB, woutB);

  // 1. yt = LN1(x), all batches
  ln_t_kernel<<<dim3(256, 4), 256, 0, stream>>>(x, ln1w, ln1b, yt);
  // 2. qkva = w_qkv @ y   (576 x 16384) x4
  mfma_gemm<0><<<dim3(9, 128, 4), 256, 0, stream>>>(
      wqkvB, yt, nullptr, qkva, 576, HW, 192,
      (size_t)HW * 192, 0, (size_t)576 * HW);
  // 3. qkvb = dwconv3x3(qkva) + nrm2 partials
  dw_kernel<<<dim3(8, 576, 4), 256, 0, stream>>>(qkva, wqkvdw, qkvb, nrm2p);
  // 4. Gram partials via MFMA
  gram_kernel<<<dim3(8, 32, 4), 256, 0, stream>>>(qkvb, Gpart);
  // 5. P = softmax(reduce(Gpart) * temp / (|q||k|))
  softmax2_kernel<<<dim3(8, 4), 256, 0, stream>>>(Gpart, nrm2p, temp, P);
  // 6. yt = (P @ v)^T bf16
  pv_kernel<<<dim3(8, 64, 4), 256, 0, stream>>>(P, qkvb, yt);
  // 7. xa = x + w_proj @ pv
  mfma_gemm<1><<<dim3(3, 128, 4), 256, 0, stream>>>(
      wprojB, yt, x, xa, 192, HW, 192,
      (size_t)HW * 192, HWC, HWC);
  // 8. yt = LN2(xa)
  ln_t_kernel<<<dim3(256, 4), 256, 0, stream>>>(xa, ln2w, ln2b, yt);
  // 9. hbuf = w_in @ y   (1020 x 16384) x4  (overwrites dead qkva/qkvb)
  mfma_gemm<0><<<dim3(16, 128, 4), 256, 0, stream>>>(
      winB, yt, nullptr, hbuf, 1020, HW, 192,
      (size_t)HW * 192, 0, (size_t)1024 * HW);
  // 10-13. FFN tail in two half-batches: gate(+transpose) then w_out GEMM
  for (int half = 0; half < 2; half++) {
    const int b0 = half * 2;
    dwg_t_kernel<<<dim3(32, 16, 2), 256, 0, stream>>>(hbuf, wdw, gt, b0);
    mfma_gemm<1><<<dim3(3, 128, 2), 256, 0, stream>>>(
        woutB, gt, xa + (size_t)b0 * HWC, out + (size_t)b0 * HWC,
        192, HW, 512, (size_t)HW * 512, HWC, HWC);
  }
}